// Round 1
// baseline (1772.238 us; speedup 1.0000x reference)
//
#include <hip/hip_runtime.h>
#include <math.h>

#define EPS 1e-5f

// ---------------- Kernel A: conv1 (two branches, concat) + bn1 + leaky + pool ----------------
// x: [256][4096][2] -> out1: [256][32][2047]
__global__ __launch_bounds__(256) void kA(const float* __restrict__ x,
    const float* __restrict__ w1a, const float* __restrict__ w1b,
    const float* __restrict__ g, const float* __restrict__ bta,
    const float* __restrict__ mn, const float* __restrict__ vr,
    float* __restrict__ out1) {
  int t = blockIdx.x * 256 + threadIdx.x;
  int c = blockIdx.y;
  int b = blockIdx.z;
  if (t >= 2047) return;
  // positions l = 2t-1 .. 2t+3  (5 positions, 2 input channels)
  float xv0[5], xv1[5];
  const float* xb = x + (size_t)b * 4096 * 2;
#pragma unroll
  for (int j = 0; j < 5; j++) {
    int l = 2 * t - 1 + j;
    if (l >= 0 && l < 4096) { xv0[j] = xb[l * 2]; xv1[j] = xb[l * 2 + 1]; }
    else { xv0[j] = 0.f; xv1[j] = 0.f; }
  }
  float a0 = 0.f, a1 = 0.f;
  if (c < 16) {
    // conv1a: kernel 4, pad 1 left: out[p] = sum_k x[p-1+k] * w
#pragma unroll
    for (int k = 0; k < 4; k++) {
      float wk0 = w1a[c * 8 + k];
      float wk1 = w1a[c * 8 + 4 + k];
      a0 += xv0[k] * wk0 + xv1[k] * wk1;         // p = 2t   -> j = k
      a1 += xv0[k + 1] * wk0 + xv1[k + 1] * wk1; // p = 2t+1 -> j = k+1
    }
  } else {
    int cc = c - 16; // conv1b: kernel 2, no pad
#pragma unroll
    for (int k = 0; k < 2; k++) {
      float wk0 = w1b[cc * 4 + k];
      float wk1 = w1b[cc * 4 + 2 + k];
      a0 += xv0[k + 1] * wk0 + xv1[k + 1] * wk1;
      a1 += xv0[k + 2] * wk0 + xv1[k + 2] * wk1;
    }
  }
  float sc = g[c] * rsqrtf(vr[c] + EPS);
  float sh = bta[c] - mn[c] * sc;
  a0 = a0 * sc + sh; a1 = a1 * sc + sh;
  a0 = a0 >= 0.f ? a0 : 0.01f * a0;
  a1 = a1 >= 0.f ? a1 : 0.01f * a1;
  out1[((size_t)b * 32 + c) * 2047 + t] = fmaxf(a0, a1);
}

// ---------------- Templated conv stage: conv(k=3,no pad) + bn + leaky + pool ----------------
// in: [B][IC][LIN] -> out: [B][OC][LOUT], LOUT = (LIN-2)/2
// Block: 256 threads = 4 waves; lane = t offset (64 t per block), each wave does NC=OC/4 channels.
template<int IC, int OC, int LIN, int LOUT, int CHUNK, int NC>
__global__ __launch_bounds__(256) void kConv(const float* __restrict__ in,
    const float* __restrict__ w, const float* __restrict__ g,
    const float* __restrict__ bta, const float* __restrict__ mn,
    const float* __restrict__ vr, float* __restrict__ out) {
  constexpr int ISTR = 132;
  constexpr int LOG_OC = (OC == 64) ? 6 : 7;
  __shared__ float in_tile[IC * ISTR];
  __shared__ float wT[CHUNK * 3 * OC];
  int tid = threadIdx.x;
  int lane = tid & 63, wv = tid >> 6;
  int b = blockIdx.z;
  int t0 = blockIdx.x * 64;
  // load input tile: positions 2*t0 .. 2*t0+129
  {
    int r = tid >> 3, j = tid & 7;
    for (int ci = r; ci < IC; ci += 32) {
      const float* src = in + ((size_t)b * IC + ci) * LIN + 2 * t0;
      for (int p = j; p < 130; p += 8) {
        int gp = 2 * t0 + p;
        in_tile[ci * ISTR + p] = (gp < LIN) ? src[p] : 0.f;
      }
    }
  }
  float accA[NC], accB[NC];
#pragma unroll
  for (int i = 0; i < NC; i++) { accA[i] = 0.f; accB[i] = 0.f; }
  int c_base = wv * NC;
  for (int ci0 = 0; ci0 < IC; ci0 += CHUNK) {
    __syncthreads();
    // stage weight chunk transposed: wT[(ci_l*3+k)*OC + cc] = w[cc][ci0+ci_l][k]
    for (int idx = tid; idx < CHUNK * 3 * OC; idx += 256) {
      int cc = idx & (OC - 1);
      int r = idx >> LOG_OC;
      int ci_l = r / 3, k = r - 3 * ci_l;
      wT[idx] = w[cc * IC * 3 + (ci0 + ci_l) * 3 + k];
    }
    __syncthreads();
#pragma unroll 2
    for (int ci_l = 0; ci_l < CHUNK; ci_l++) {
      const float* ip = in_tile + (ci0 + ci_l) * ISTR + 2 * lane;
      float x0 = ip[0], x1 = ip[1], x2 = ip[2], x3 = ip[3];
      const float* wr = wT + ci_l * 3 * OC + c_base;
#pragma unroll
      for (int c4 = 0; c4 < NC; c4 += 4) {
        float4 w0 = *(const float4*)(wr + c4);
        float4 w1 = *(const float4*)(wr + OC + c4);
        float4 w2 = *(const float4*)(wr + 2 * OC + c4);
        accA[c4 + 0] += x0 * w0.x + x1 * w1.x + x2 * w2.x;
        accB[c4 + 0] += x1 * w0.x + x2 * w1.x + x3 * w2.x;
        accA[c4 + 1] += x0 * w0.y + x1 * w1.y + x2 * w2.y;
        accB[c4 + 1] += x1 * w0.y + x2 * w1.y + x3 * w2.y;
        accA[c4 + 2] += x0 * w0.z + x1 * w1.z + x2 * w2.z;
        accB[c4 + 2] += x1 * w0.z + x2 * w1.z + x3 * w2.z;
        accA[c4 + 3] += x0 * w0.w + x1 * w1.w + x2 * w2.w;
        accB[c4 + 3] += x1 * w0.w + x2 * w1.w + x3 * w2.w;
      }
    }
  }
  int t = t0 + lane;
  if (t < LOUT) {
#pragma unroll
    for (int i = 0; i < NC; i++) {
      int cc = c_base + i;
      float sc = g[cc] * rsqrtf(vr[cc] + EPS);
      float sh = bta[cc] - mn[cc] * sc;
      float a = accA[i] * sc + sh, bb = accB[i] * sc + sh;
      a = a >= 0.f ? a : 0.01f * a;
      bb = bb >= 0.f ? bb : 0.01f * bb;
      out[((size_t)b * OC + cc) * LOUT + t] = fmaxf(a, bb);
    }
  }
}

// ---------------- LN over channels (transpose) -> xn ; also capture e_last (t=509) ----------------
// h3: [256][128][510] -> xn: [256][510][128]
__global__ __launch_bounds__(256) void kLN1(const float* __restrict__ h3,
    const float* __restrict__ lnw, float* __restrict__ xn, float* __restrict__ elast) {
  __shared__ float tile[128 * 65];
  __shared__ float smu[64], srs[64];
  int tid = threadIdx.x;
  int b = blockIdx.z;
  int t0 = blockIdx.x * 64;
  {
    int tt = tid & 63, c0 = tid >> 6;
    for (int it = 0; it < 32; it++) {
      int c = c0 + it * 4;
      int t = t0 + tt;
      tile[c * 65 + tt] = (t < 510) ? h3[((size_t)b * 128 + c) * 510 + t] : 0.f;
    }
  }
  __syncthreads();
  {
    int tl = tid >> 2, q = tid & 3;
    float s1 = 0.f, s2 = 0.f;
    for (int j = 0; j < 32; j++) {
      float v = tile[(q * 32 + j) * 65 + tl];
      s1 += v; s2 += v * v;
    }
    s1 += __shfl_xor(s1, 1); s2 += __shfl_xor(s2, 1);
    s1 += __shfl_xor(s1, 2); s2 += __shfl_xor(s2, 2);
    if (q == 0) {
      float mu = s1 * (1.f / 128.f);
      float var = s2 * (1.f / 128.f) - mu * mu;
      smu[tl] = mu; srs[tl] = rsqrtf(var + EPS);
    }
  }
  __syncthreads();
  {
    int c = tid & 127, th = tid >> 7;
    for (int tt = th; tt < 64; tt += 2) {
      int t = t0 + tt;
      if (t < 510) {
        float v = tile[c * 65 + tt];
        xn[((size_t)b * 510 + t) * 128 + c] = (v - smu[tt]) * srs[tt] * lnw[c];
        if (t == 509) elast[b * 128 + c] = v;
      }
    }
  }
}

// ---------------- Causal depthwise conv (k=3, left pad 2) + bias + SiLU ----------------
__global__ __launch_bounds__(256) void kDW(const float* __restrict__ xn,
    const float* __restrict__ cw, const float* __restrict__ cb,
    float* __restrict__ xcv) {
  int d = threadIdx.x & 127;
  int s = blockIdx.x * 2 + (threadIdx.x >> 7);
  int b = blockIdx.z;
  const float* row = xn + ((size_t)b * 510 + s) * 128 + d;
  float acc = cb[d];
  float w0 = cw[d * 3], w1 = cw[d * 3 + 1], w2 = cw[d * 3 + 2];
  if (s >= 2) acc += row[-256] * w0;
  if (s >= 1) acc += row[-128] * w1;
  acc += row[0] * w2;
  xcv[((size_t)b * 510 + s) * 128 + d] = acc / (1.f + expf(-acc));
}

// ---------------- Fused gate projection + sLSTM recurrence, one wave per (b,h) ----------------
// lanes 0-31: gates i (from xcv) / z (from xn) for e=lane; lanes 32-63: f (xcv) / o (xn), e=lane-32.
// State (c,n,m,y) lives on lanes 0-31 indexed by e.
__global__ __launch_bounds__(64) void kRec(const float* __restrict__ xcv,
    const float* __restrict__ xn, const float* __restrict__ wi,
    const float* __restrict__ wf, const float* __restrict__ wz,
    const float* __restrict__ wo, const float* __restrict__ rk,
    const float* __restrict__ rb, float* __restrict__ yf) {
  int bh = blockIdx.x; int b = bh >> 2, h = bh & 3;
  int l = threadIdx.x; int half = l >> 5; int e = l & 31;
  float W1[32], W2[32], R1[32], R2[32];
  const float* w1p = (half ? wf : wi) + h * 1024 + e;  // [h][d][e]
  const float* w2p = (half ? wo : wz) + h * 1024 + e;
  int g1 = half, g2 = 2 + half;
  const float* r1p = rk + h * 4096 + g1 * 32 + e;      // rk[h][d][g][e]
  const float* r2p = rk + h * 4096 + g2 * 32 + e;
#pragma unroll
  for (int d = 0; d < 32; d++) {
    W1[d] = w1p[d * 32]; W2[d] = w2p[d * 32];
    R1[d] = r1p[d * 128]; R2[d] = r2p[d * 128];
  }
  float rb1 = rb[g1 * 128 + h * 32 + e];
  float rb2 = rb[g2 * 128 + h * 32 + e];
  // per-lane source load: lanes<32 load xcv slice, lanes>=32 load xn slice (both rows broadcast via shfl)
  const float* src = (half ? xn : xcv) + (size_t)b * 510 * 128 + h * 32 + e;
  float y = 0.f, cst = 0.f, nst = 0.f, mst = 0.f;
  float v = src[0];
  float pre1 = rb1, pre2 = rb2;
#pragma unroll
  for (int d = 0; d < 32; d++) {
    pre1 += __shfl(v, d) * W1[d];        // xcv[d]
    pre2 += __shfl(v, d + 32) * W2[d];   // xn[d]
  }
  for (int s = 0; s < 510; s++) {
    float vn = (s < 509) ? src[(size_t)(s + 1) * 128] : 0.f;
    float a1 = pre1, a2 = pre2;
#pragma unroll
    for (int d = 0; d < 32; d++) {
      float yd = __shfl(y, d);
      a1 += yd * R1[d];
      a2 += yd * R2[d];
    }
    // lanes>=32: a1=fraw -> logsig ; a2=oraw -> sigmoid. lanes<32: a1=iraw ; a2=zraw -> tanh
    float ls = fminf(a1, 0.f) - log1pf(expf(-fabsf(a1)));
    float sg = 1.f / (1.f + expf(-a2));
    float tz = tanhf(a2);
    float lsf = __shfl(ls, (l + 32) & 63);
    float so  = __shfl(sg, (l + 32) & 63);
    float lf = mst + lsf;
    float mnew = fmaxf(a1, lf);            // a1 = iraw on lanes<32
    float ig = expf(a1 - mnew);
    float fg = expf(lf - mnew);
    cst = fg * cst + ig * tz;
    nst = fg * nst + ig;
    mst = mnew;
    y = so * cst / nst;
    // next step's feedforward part (independent of y -> overlaps the matvec chain)
    pre1 = rb1; pre2 = rb2;
#pragma unroll
    for (int d = 0; d < 32; d++) {
      pre1 += __shfl(vn, d) * W1[d];
      pre2 += __shfl(vn, d + 32) * W2[d];
    }
    v = vn;
  }
  if (half == 0) yf[b * 128 + h * 32 + e] = y;
}

// ---------------- Tail for the last timestep only: GN + residual + LN + GeGLU FFN + LN + FC ----------------
__global__ __launch_bounds__(128) void kHead(const float* __restrict__ yf,
    const float* __restrict__ elast, const float* __restrict__ gnw,
    const float* __restrict__ ln2w, const float* __restrict__ upw,
    const float* __restrict__ dnw, const float* __restrict__ lnpw,
    const float* __restrict__ fcw, const float* __restrict__ fcb,
    float* __restrict__ outp) {
  int c = threadIdx.x; int b = blockIdx.x;
  __shared__ float sred[4];
  __shared__ float sx[128];
  __shared__ float sup[384];
  __shared__ float shh[192];
  float yv = yf[b * 128 + c];
  // GroupNorm over DH=32 within each head
  float s1 = yv, s2 = yv * yv;
#pragma unroll
  for (int m = 1; m <= 16; m <<= 1) { s1 += __shfl_xor(s1, m); s2 += __shfl_xor(s2, m); }
  float mu = s1 * (1.f / 32.f);
  float var = s2 * (1.f / 32.f) - mu * mu;
  float yn = (yv - mu) * rsqrtf(var + EPS) * gnw[c];
  float el = elast[b * 128 + c] + yn;
  auto ln128 = [&](float v, const float* w) -> float {
    float a = v, a2 = v * v;
#pragma unroll
    for (int m = 1; m <= 32; m <<= 1) { a += __shfl_xor(a, m); a2 += __shfl_xor(a2, m); }
    int wv = c >> 6;
    if ((c & 63) == 0) { sred[wv * 2] = a; sred[wv * 2 + 1] = a2; }
    __syncthreads();
    float t1 = sred[0] + sred[2], t2 = sred[1] + sred[3];
    __syncthreads();
    float mm = t1 * (1.f / 128.f);
    float vv = t2 * (1.f / 128.f) - mm * mm;
    return (v - mm) * rsqrtf(vv + EPS) * w[c];
  };
  float xn2 = ln128(el, ln2w);
  sx[c] = xn2;
  __syncthreads();
#pragma unroll
  for (int jj = 0; jj < 3; jj++) {
    int j = c + jj * 128;
    float acc = 0.f;
    for (int k = 0; k < 128; k++) acc += sx[k] * upw[k * 384 + j];
    sup[j] = acc;
  }
  __syncthreads();
  {
    float u = sup[c]; float mg = sup[192 + c];
    shh[c] = 0.5f * u * (1.f + erff(u * 0.70710678118654752f)) * mg;
    if (c < 64) {
      float u2 = sup[128 + c]; float m2 = sup[320 + c];
      shh[128 + c] = 0.5f * u2 * (1.f + erff(u2 * 0.70710678118654752f)) * m2;
    }
  }
  __syncthreads();
  float acc = 0.f;
  for (int f = 0; f < 192; f++) acc += shh[f] * dnw[f * 128 + c];
  float e2 = el + acc;
  float e3 = ln128(e2, lnpw);
  sx[c] = e3;
  __syncthreads();
  if (c < 5) {
    float a = fcb[c];
    for (int k = 0; k < 128; k++) a += sx[k] * fcw[k * 5 + c];
    outp[b * 5 + c] = a;
  }
}

extern "C" void kernel_launch(void* const* d_in, const int* in_sizes, int n_in,
                              void* d_out, int out_size, void* d_ws, size_t ws_size,
                              hipStream_t stream) {
  const float* x    = (const float*)d_in[0];
  const float* w1a  = (const float*)d_in[1];
  const float* w1b  = (const float*)d_in[2];
  const float* bn1g = (const float*)d_in[3];
  const float* bn1b = (const float*)d_in[4];
  const float* bn1m = (const float*)d_in[5];
  const float* bn1v = (const float*)d_in[6];
  const float* w2   = (const float*)d_in[7];
  const float* bn2g = (const float*)d_in[8];
  const float* bn2b = (const float*)d_in[9];
  const float* bn2m = (const float*)d_in[10];
  const float* bn2v = (const float*)d_in[11];
  const float* w3   = (const float*)d_in[12];
  const float* bn3g = (const float*)d_in[13];
  const float* bn3b = (const float*)d_in[14];
  const float* bn3m = (const float*)d_in[15];
  const float* bn3v = (const float*)d_in[16];
  const float* ln1w = (const float*)d_in[17];
  const float* cw   = (const float*)d_in[18];
  const float* cb   = (const float*)d_in[19];
  const float* wi   = (const float*)d_in[20];
  const float* wf   = (const float*)d_in[21];
  const float* wz   = (const float*)d_in[22];
  const float* wo   = (const float*)d_in[23];
  const float* rk   = (const float*)d_in[24];
  const float* rb   = (const float*)d_in[25];
  const float* gnw  = (const float*)d_in[26];
  const float* ln2w = (const float*)d_in[27];
  const float* upw  = (const float*)d_in[28];
  const float* dnw  = (const float*)d_in[29];
  const float* lnpw = (const float*)d_in[30];
  const float* fcw  = (const float*)d_in[31];
  const float* fcb  = (const float*)d_in[32];
  float* outp = (float*)d_out;

  char* ws = (char*)d_ws;
  float* buf1  = (float*)ws;                                   // 64 MiB ping
  float* buf2  = (float*)(ws + ((size_t)64 << 20));            // 64 MiB pong
  float* elast = (float*)(ws + ((size_t)128 << 20));           // [256][128]
  float* yfin  = (float*)(ws + ((size_t)129 << 20));           // [256][128]

  float* out1 = buf1;  // [256][32][2047]
  float* out2 = buf2;  // [256][64][1022]
  float* h3   = buf1;  // [256][128][510]  (out1 dead)
  float* xnb  = buf2;  // [256][510][128]  (out2 dead)
  float* xcvb = buf1;  // [256][510][128]  (h3 dead)

  kA<<<dim3(8, 32, 256), 256, 0, stream>>>(x, w1a, w1b, bn1g, bn1b, bn1m, bn1v, out1);
  kConv<32, 64, 2047, 1022, 32, 16><<<dim3(16, 1, 256), 256, 0, stream>>>(
      out1, w2, bn2g, bn2b, bn2m, bn2v, out2);
  kConv<64, 128, 1022, 510, 16, 32><<<dim3(8, 1, 256), 256, 0, stream>>>(
      out2, w3, bn3g, bn3b, bn3m, bn3v, h3);
  kLN1<<<dim3(8, 1, 256), 256, 0, stream>>>(h3, ln1w, xnb, elast);
  kDW<<<dim3(255, 1, 256), 256, 0, stream>>>(xnb, cw, cb, xcvb);
  kRec<<<dim3(1024), 64, 0, stream>>>(xcvb, xnb, wi, wf, wz, wo, rk, rb, yfin);
  kHead<<<dim3(256), 128, 0, stream>>>(yfin, elast, gnw, ln2w, upw, dnw, lnpw, fcw, fcb, outp);
}

// Round 2
// 1640.380 us; speedup vs baseline: 1.0804x; 1.0804x over previous
//
#include <hip/hip_runtime.h>
#include <hip/hip_bf16.h>
#include <math.h>

#define EPS 1e-5f

// ---------------- Kernel A: conv1 (two branches, concat) + bn1 + leaky + pool ----------------
// x: [256][4096][2] -> out1: [256][32][2047]
__global__ __launch_bounds__(256) void kA(const float* __restrict__ x,
    const float* __restrict__ w1a, const float* __restrict__ w1b,
    const float* __restrict__ g, const float* __restrict__ bta,
    const float* __restrict__ mn, const float* __restrict__ vr,
    float* __restrict__ out1) {
  int t = blockIdx.x * 256 + threadIdx.x;
  int c = blockIdx.y;
  int b = blockIdx.z;
  if (t >= 2047) return;
  float xv0[5], xv1[5];
  const float* xb = x + (size_t)b * 4096 * 2;
#pragma unroll
  for (int j = 0; j < 5; j++) {
    int l = 2 * t - 1 + j;
    if (l >= 0 && l < 4096) { xv0[j] = xb[l * 2]; xv1[j] = xb[l * 2 + 1]; }
    else { xv0[j] = 0.f; xv1[j] = 0.f; }
  }
  float a0 = 0.f, a1 = 0.f;
  if (c < 16) {
#pragma unroll
    for (int k = 0; k < 4; k++) {
      float wk0 = w1a[c * 8 + k];
      float wk1 = w1a[c * 8 + 4 + k];
      a0 += xv0[k] * wk0 + xv1[k] * wk1;
      a1 += xv0[k + 1] * wk0 + xv1[k + 1] * wk1;
    }
  } else {
    int cc = c - 16;
#pragma unroll
    for (int k = 0; k < 2; k++) {
      float wk0 = w1b[cc * 4 + k];
      float wk1 = w1b[cc * 4 + 2 + k];
      a0 += xv0[k + 1] * wk0 + xv1[k + 1] * wk1;
      a1 += xv0[k + 2] * wk0 + xv1[k + 2] * wk1;
    }
  }
  float sc = g[c] * rsqrtf(vr[c] + EPS);
  float sh = bta[c] - mn[c] * sc;
  a0 = a0 * sc + sh; a1 = a1 * sc + sh;
  a0 = a0 >= 0.f ? a0 : 0.01f * a0;
  a1 = a1 >= 0.f ? a1 : 0.01f * a1;
  out1[((size_t)b * 32 + c) * 2047 + t] = fmaxf(a0, a1);
}

// ---------------- Templated conv stage: conv(k=3,no pad) + bn + leaky + pool ----------------
template<int IC, int OC, int LIN, int LOUT, int CHUNK, int NC>
__global__ __launch_bounds__(256) void kConv(const float* __restrict__ in,
    const float* __restrict__ w, const float* __restrict__ g,
    const float* __restrict__ bta, const float* __restrict__ mn,
    const float* __restrict__ vr, float* __restrict__ out) {
  constexpr int ISTR = 132;
  constexpr int LOG_OC = (OC == 64) ? 6 : 7;
  __shared__ float in_tile[IC * ISTR];
  __shared__ float wT[CHUNK * 3 * OC];
  int tid = threadIdx.x;
  int lane = tid & 63, wv = tid >> 6;
  int b = blockIdx.z;
  int t0 = blockIdx.x * 64;
  {
    int r = tid >> 3, j = tid & 7;
    for (int ci = r; ci < IC; ci += 32) {
      const float* src = in + ((size_t)b * IC + ci) * LIN + 2 * t0;
      for (int p = j; p < 130; p += 8) {
        int gp = 2 * t0 + p;
        in_tile[ci * ISTR + p] = (gp < LIN) ? src[p] : 0.f;
      }
    }
  }
  float accA[NC], accB[NC];
#pragma unroll
  for (int i = 0; i < NC; i++) { accA[i] = 0.f; accB[i] = 0.f; }
  int c_base = wv * NC;
  for (int ci0 = 0; ci0 < IC; ci0 += CHUNK) {
    __syncthreads();
    for (int idx = tid; idx < CHUNK * 3 * OC; idx += 256) {
      int cc = idx & (OC - 1);
      int r = idx >> LOG_OC;
      int ci_l = r / 3, k = r - 3 * ci_l;
      wT[idx] = w[cc * IC * 3 + (ci0 + ci_l) * 3 + k];
    }
    __syncthreads();
#pragma unroll 2
    for (int ci_l = 0; ci_l < CHUNK; ci_l++) {
      const float* ip = in_tile + (ci0 + ci_l) * ISTR + 2 * lane;
      float x0 = ip[0], x1 = ip[1], x2 = ip[2], x3 = ip[3];
      const float* wr = wT + ci_l * 3 * OC + c_base;
#pragma unroll
      for (int c4 = 0; c4 < NC; c4 += 4) {
        float4 w0 = *(const float4*)(wr + c4);
        float4 w1 = *(const float4*)(wr + OC + c4);
        float4 w2 = *(const float4*)(wr + 2 * OC + c4);
        accA[c4 + 0] += x0 * w0.x + x1 * w1.x + x2 * w2.x;
        accB[c4 + 0] += x1 * w0.x + x2 * w1.x + x3 * w2.x;
        accA[c4 + 1] += x0 * w0.y + x1 * w1.y + x2 * w2.y;
        accB[c4 + 1] += x1 * w0.y + x2 * w1.y + x3 * w2.y;
        accA[c4 + 2] += x0 * w0.z + x1 * w1.z + x2 * w2.z;
        accB[c4 + 2] += x1 * w0.z + x2 * w1.z + x3 * w2.z;
        accA[c4 + 3] += x0 * w0.w + x1 * w1.w + x2 * w2.w;
        accB[c4 + 3] += x1 * w0.w + x2 * w1.w + x3 * w2.w;
      }
    }
  }
  int t = t0 + lane;
  if (t < LOUT) {
#pragma unroll
    for (int i = 0; i < NC; i++) {
      int cc = c_base + i;
      float sc = g[cc] * rsqrtf(vr[cc] + EPS);
      float sh = bta[cc] - mn[cc] * sc;
      float a = accA[i] * sc + sh, bb = accB[i] * sc + sh;
      a = a >= 0.f ? a : 0.01f * a;
      bb = bb >= 0.f ? bb : 0.01f * bb;
      out[((size_t)b * OC + cc) * LOUT + t] = fmaxf(a, bb);
    }
  }
}

// ---------------- LN over channels (transpose) -> xn ; also capture e_last (t=509) ----------------
__global__ __launch_bounds__(256) void kLN1(const float* __restrict__ h3,
    const float* __restrict__ lnw, float* __restrict__ xn, float* __restrict__ elast) {
  __shared__ float tile[128 * 65];
  __shared__ float smu[64], srs[64];
  int tid = threadIdx.x;
  int b = blockIdx.z;
  int t0 = blockIdx.x * 64;
  {
    int tt = tid & 63, c0 = tid >> 6;
    for (int it = 0; it < 32; it++) {
      int c = c0 + it * 4;
      int t = t0 + tt;
      tile[c * 65 + tt] = (t < 510) ? h3[((size_t)b * 128 + c) * 510 + t] : 0.f;
    }
  }
  __syncthreads();
  {
    int tl = tid >> 2, q = tid & 3;
    float s1 = 0.f, s2 = 0.f;
    for (int j = 0; j < 32; j++) {
      float v = tile[(q * 32 + j) * 65 + tl];
      s1 += v; s2 += v * v;
    }
    s1 += __shfl_xor(s1, 1); s2 += __shfl_xor(s2, 1);
    s1 += __shfl_xor(s1, 2); s2 += __shfl_xor(s2, 2);
    if (q == 0) {
      float mu = s1 * (1.f / 128.f);
      float var = s2 * (1.f / 128.f) - mu * mu;
      smu[tl] = mu; srs[tl] = rsqrtf(var + EPS);
    }
  }
  __syncthreads();
  {
    int c = tid & 127, th = tid >> 7;
    for (int tt = th; tt < 64; tt += 2) {
      int t = t0 + tt;
      if (t < 510) {
        float v = tile[c * 65 + tt];
        xn[((size_t)b * 510 + t) * 128 + c] = (v - smu[tt]) * srs[tt] * lnw[c];
        if (t == 509) elast[b * 128 + c] = v;
      }
    }
  }
}

// ---------------- Causal depthwise conv (k=3, left pad 2) + bias + SiLU ----------------
__global__ __launch_bounds__(256) void kDW(const float* __restrict__ xn,
    const float* __restrict__ cw, const float* __restrict__ cb,
    float* __restrict__ xcv) {
  int d = threadIdx.x & 127;
  int s = blockIdx.x * 2 + (threadIdx.x >> 7);
  int b = blockIdx.z;
  const float* row = xn + ((size_t)b * 510 + s) * 128 + d;
  float acc = cb[d];
  float w0 = cw[d * 3], w1 = cw[d * 3 + 1], w2 = cw[d * 3 + 2];
  if (s >= 2) acc += row[-256] * w0;
  if (s >= 1) acc += row[-128] * w1;
  acc += row[0] * w2;
  xcv[((size_t)b * 510 + s) * 128 + d] = acc / (1.f + expf(-acc));
}

// ---------------- Gate input-projections for ALL timesteps (y-independent part) ----------------
// out gx[s][bh][j] bf16 where j = l*2+slot: slot0 = pre(i/f gate) from xcv, slot1 = pre(z/o) from xn,
// l = half*32+e matches kRec's lane layout.
__global__ __launch_bounds__(256) void kGx(const float* __restrict__ xcv,
    const float* __restrict__ xn, const float* __restrict__ wi,
    const float* __restrict__ wf, const float* __restrict__ wz,
    const float* __restrict__ wo, const float* __restrict__ rb,
    __hip_bfloat16* __restrict__ gx) {
  __shared__ float lbuf[128];  // [s_i][src][d] = s_i*64 + src*32 + d
  int bh = blockIdx.x; int b = bh >> 2, h = bh & 3;
  int t = threadIdx.x;
  int sOff = t >> 7, j = t & 127, slot = j & 1, l = j >> 1;
  int halfg = l >> 5, e = l & 31;
  const float* wp = (slot == 0) ? (halfg ? wf : wi) : (halfg ? wo : wz);
  wp += h * 1024 + e;
  float W[32];
#pragma unroll
  for (int d = 0; d < 32; d++) W[d] = wp[d * 32];
  int gate = slot * 2 + halfg;
  float bias = rb[gate * 128 + h * 32 + e];
  // loader mapping (threads 0-127): s_i = t>>6, src_i = (t>>5)&1, d = t&31
  int ld_s = (t >> 6) & 1, ld_src = (t >> 5) & 1, ld_d = t & 31;
  const float* srcp = (ld_src ? xn : xcv) + ((size_t)b * 510) * 128 + h * 32 + ld_d;
  for (int s0 = 0; s0 < 510; s0 += 2) {
    __syncthreads();
    if (t < 128) lbuf[t] = srcp[(size_t)(s0 + ld_s) * 128];
    __syncthreads();
    const float* ib = lbuf + sOff * 64 + slot * 32;
    float acc = bias;
#pragma unroll
    for (int q = 0; q < 8; q++) {
      float4 v = *(const float4*)(ib + 4 * q);
      acc += v.x * W[4 * q] + v.y * W[4 * q + 1] + v.z * W[4 * q + 2] + v.w * W[4 * q + 3];
    }
    int s = s0 + sOff;
    gx[((size_t)s * 1024 + bh) * 128 + j] = __float2bfloat16(acc);
  }
}

// ---------------- Lean sLSTM recurrence: gx prefetch + LDS y-broadcast ----------------
// wave = (b,h). lanes: half = l>>5, e = l&31. half0: gates i(pre1)/z(pre2); half1: f/o.
__global__ __launch_bounds__(64) void kRec(const unsigned int* __restrict__ gx,
    const float* __restrict__ rk, float* __restrict__ yf) {
  __shared__ float ybuf[64];
  __shared__ float xbuf[128];
  int bh = blockIdx.x; int b = bh >> 2, h = bh & 3;
  int l = threadIdx.x; int half = l >> 5; int e = l & 31;
  float R1[32], R2[32];
  int g1 = half, g2 = 2 + half;
  const float* r1p = rk + h * 4096 + g1 * 32 + e;
  const float* r2p = rk + h * 4096 + g2 * 32 + e;
#pragma unroll
  for (int d = 0; d < 32; d++) { R1[d] = r1p[d * 128]; R2[d] = r2p[d * 128]; }
  const unsigned int* gp = gx + (size_t)bh * 64 + l;  // per-s stride = 65536 uints
  unsigned int p0 = gp[0], p1 = gp[65536], p2 = gp[2 * 65536];
  float y = 0.f, cst = 0.f, nst = 0.f, mst = 0.f;
  ybuf[l] = 0.f;
  for (int s = 0; s < 510; s++) {
    unsigned int pc = p0; p0 = p1; p1 = p2;
    if (s + 3 < 510) p2 = gp[(size_t)(s + 3) * 65536];
    float a1 = __uint_as_float(pc << 16);          // pre1 (i/f)
    float a2 = __uint_as_float(pc & 0xFFFF0000u);  // pre2 (z/o)
    // y matvec via LDS broadcast (reads follow last iter's write; DS pipe is in-order per wave)
#pragma unroll
    for (int q = 0; q < 8; q++) {
      float4 yv = *(const float4*)(ybuf + 4 * q);
      a1 += yv.x * R1[4 * q] + yv.y * R1[4 * q + 1] + yv.z * R1[4 * q + 2] + yv.w * R1[4 * q + 3];
      a2 += yv.x * R2[4 * q] + yv.y * R2[4 * q + 1] + yv.z * R2[4 * q + 2] + yv.w * R2[4 * q + 3];
    }
    float ls = fminf(a1, 0.f) - log1pf(expf(-fabsf(a1)));  // log-sigmoid(a1)
    float sg = 1.f / (1.f + expf(-a2));                    // sigmoid(a2)
    xbuf[2 * l] = ls; xbuf[2 * l + 1] = sg;
    float tz = tanhf(a2);
    float lsf = xbuf[2 * (l | 32)];      // half0 reads half1's logsig(fraw)
    float so  = xbuf[2 * (l | 32) + 1];  // half0 reads half1's sigmoid(oraw)
    float lf = mst + lsf;
    float mnew = fmaxf(a1, lf);          // a1 = iraw on half0
    float ig = expf(a1 - mnew);
    float fg = expf(lf - mnew);
    cst = fg * cst + ig * tz;
    nst = fg * nst + ig;
    mst = mnew;
    y = so * cst / nst;
    ybuf[l] = y;  // half0 -> slots 0..31 (valid); half1 -> dummy slots 32..63
  }
  if (half == 0) yf[b * 128 + h * 32 + e] = y;
}

// ---------------- Tail for the last timestep only ----------------
__global__ __launch_bounds__(128) void kHead(const float* __restrict__ yf,
    const float* __restrict__ elast, const float* __restrict__ gnw,
    const float* __restrict__ ln2w, const float* __restrict__ upw,
    const float* __restrict__ dnw, const float* __restrict__ lnpw,
    const float* __restrict__ fcw, const float* __restrict__ fcb,
    float* __restrict__ outp) {
  int c = threadIdx.x; int b = blockIdx.x;
  __shared__ float sred[4];
  __shared__ float sx[128];
  __shared__ float sup[384];
  __shared__ float shh[192];
  float yv = yf[b * 128 + c];
  float s1 = yv, s2 = yv * yv;
#pragma unroll
  for (int m = 1; m <= 16; m <<= 1) { s1 += __shfl_xor(s1, m); s2 += __shfl_xor(s2, m); }
  float mu = s1 * (1.f / 32.f);
  float var = s2 * (1.f / 32.f) - mu * mu;
  float yn = (yv - mu) * rsqrtf(var + EPS) * gnw[c];
  float el = elast[b * 128 + c] + yn;
  auto ln128 = [&](float v, const float* w) -> float {
    float a = v, a2 = v * v;
#pragma unroll
    for (int m = 1; m <= 32; m <<= 1) { a += __shfl_xor(a, m); a2 += __shfl_xor(a2, m); }
    int wv = c >> 6;
    if ((c & 63) == 0) { sred[wv * 2] = a; sred[wv * 2 + 1] = a2; }
    __syncthreads();
    float t1 = sred[0] + sred[2], t2 = sred[1] + sred[3];
    __syncthreads();
    float mm = t1 * (1.f / 128.f);
    float vv = t2 * (1.f / 128.f) - mm * mm;
    return (v - mm) * rsqrtf(vv + EPS) * w[c];
  };
  float xn2 = ln128(el, ln2w);
  sx[c] = xn2;
  __syncthreads();
#pragma unroll
  for (int jj = 0; jj < 3; jj++) {
    int j = c + jj * 128;
    float acc = 0.f;
    for (int k = 0; k < 128; k++) acc += sx[k] * upw[k * 384 + j];
    sup[j] = acc;
  }
  __syncthreads();
  {
    float u = sup[c]; float mg = sup[192 + c];
    shh[c] = 0.5f * u * (1.f + erff(u * 0.70710678118654752f)) * mg;
    if (c < 64) {
      float u2 = sup[128 + c]; float m2 = sup[320 + c];
      shh[128 + c] = 0.5f * u2 * (1.f + erff(u2 * 0.70710678118654752f)) * m2;
    }
  }
  __syncthreads();
  float acc = 0.f;
  for (int f = 0; f < 192; f++) acc += shh[f] * dnw[f * 128 + c];
  float e2 = el + acc;
  float e3 = ln128(e2, lnpw);
  sx[c] = e3;
  __syncthreads();
  if (c < 5) {
    float a = fcb[c];
    for (int k = 0; k < 128; k++) a += sx[k] * fcw[k * 5 + c];
    outp[b * 5 + c] = a;
  }
}

extern "C" void kernel_launch(void* const* d_in, const int* in_sizes, int n_in,
                              void* d_out, int out_size, void* d_ws, size_t ws_size,
                              hipStream_t stream) {
  const float* x    = (const float*)d_in[0];
  const float* w1a  = (const float*)d_in[1];
  const float* w1b  = (const float*)d_in[2];
  const float* bn1g = (const float*)d_in[3];
  const float* bn1b = (const float*)d_in[4];
  const float* bn1m = (const float*)d_in[5];
  const float* bn1v = (const float*)d_in[6];
  const float* w2   = (const float*)d_in[7];
  const float* bn2g = (const float*)d_in[8];
  const float* bn2b = (const float*)d_in[9];
  const float* bn2m = (const float*)d_in[10];
  const float* bn2v = (const float*)d_in[11];
  const float* w3   = (const float*)d_in[12];
  const float* bn3g = (const float*)d_in[13];
  const float* bn3b = (const float*)d_in[14];
  const float* bn3m = (const float*)d_in[15];
  const float* bn3v = (const float*)d_in[16];
  const float* ln1w = (const float*)d_in[17];
  const float* cw   = (const float*)d_in[18];
  const float* cb   = (const float*)d_in[19];
  const float* wi   = (const float*)d_in[20];
  const float* wf   = (const float*)d_in[21];
  const float* wz   = (const float*)d_in[22];
  const float* wo   = (const float*)d_in[23];
  const float* rk   = (const float*)d_in[24];
  const float* rb   = (const float*)d_in[25];
  const float* gnw  = (const float*)d_in[26];
  const float* ln2w = (const float*)d_in[27];
  const float* upw  = (const float*)d_in[28];
  const float* dnw  = (const float*)d_in[29];
  const float* lnpw = (const float*)d_in[30];
  const float* fcw  = (const float*)d_in[31];
  const float* fcb  = (const float*)d_in[32];
  float* outp = (float*)d_out;

  char* ws = (char*)d_ws;
  float* buf1  = (float*)ws;                                    // 64 MiB
  float* buf2  = (float*)(ws + ((size_t)64 << 20));             // 64 MiB
  __hip_bfloat16* gxb = (__hip_bfloat16*)(ws + ((size_t)128 << 20)); // 134 MB
  float* elast = (float*)(ws + ((size_t)258 << 20));
  float* yfin  = (float*)(ws + ((size_t)259 << 20));

  float* out1 = buf1;  // [256][32][2047]
  float* out2 = buf2;  // [256][64][1022]
  float* h3   = buf1;  // [256][128][510]
  float* xnb  = buf2;  // [256][510][128]
  float* xcvb = buf1;  // [256][510][128]

  kA<<<dim3(8, 32, 256), 256, 0, stream>>>(x, w1a, w1b, bn1g, bn1b, bn1m, bn1v, out1);
  kConv<32, 64, 2047, 1022, 32, 16><<<dim3(16, 1, 256), 256, 0, stream>>>(
      out1, w2, bn2g, bn2b, bn2m, bn2v, out2);
  kConv<64, 128, 1022, 510, 16, 32><<<dim3(8, 1, 256), 256, 0, stream>>>(
      out2, w3, bn3g, bn3b, bn3m, bn3v, h3);
  kLN1<<<dim3(8, 1, 256), 256, 0, stream>>>(h3, ln1w, xnb, elast);
  kDW<<<dim3(255, 1, 256), 256, 0, stream>>>(xnb, cw, cb, xcvb);
  kGx<<<dim3(1024), 256, 0, stream>>>(xcvb, xnb, wi, wf, wz, wo, rb, gxb);
  kRec<<<dim3(1024), 64, 0, stream>>>((const unsigned int*)gxb, rk, yfin);
  kHead<<<dim3(256), 128, 0, stream>>>(yfin, elast, gnw, ln2w, upw, dnw, lnpw, fcw, fcb, outp);
}

// Round 3
// 929.851 us; speedup vs baseline: 1.9059x; 1.7641x over previous
//
#include <hip/hip_runtime.h>
#include <hip/hip_bf16.h>
#include <math.h>

#define EPS 1e-5f

// ---------------- Kernel A: conv1 (two branches, concat) + bn1 + leaky + pool ----------------
// x: [256][4096][2] -> out1: [256][32][2047]
__global__ __launch_bounds__(256) void kA(const float* __restrict__ x,
    const float* __restrict__ w1a, const float* __restrict__ w1b,
    const float* __restrict__ g, const float* __restrict__ bta,
    const float* __restrict__ mn, const float* __restrict__ vr,
    float* __restrict__ out1) {
  int t = blockIdx.x * 256 + threadIdx.x;
  int c = blockIdx.y;
  int b = blockIdx.z;
  if (t >= 2047) return;
  float xv0[5], xv1[5];
  const float* xb = x + (size_t)b * 4096 * 2;
#pragma unroll
  for (int j = 0; j < 5; j++) {
    int l = 2 * t - 1 + j;
    if (l >= 0 && l < 4096) { xv0[j] = xb[l * 2]; xv1[j] = xb[l * 2 + 1]; }
    else { xv0[j] = 0.f; xv1[j] = 0.f; }
  }
  float a0 = 0.f, a1 = 0.f;
  if (c < 16) {
#pragma unroll
    for (int k = 0; k < 4; k++) {
      float wk0 = w1a[c * 8 + k];
      float wk1 = w1a[c * 8 + 4 + k];
      a0 += xv0[k] * wk0 + xv1[k] * wk1;
      a1 += xv0[k + 1] * wk0 + xv1[k + 1] * wk1;
    }
  } else {
    int cc = c - 16;
#pragma unroll
    for (int k = 0; k < 2; k++) {
      float wk0 = w1b[cc * 4 + k];
      float wk1 = w1b[cc * 4 + 2 + k];
      a0 += xv0[k + 1] * wk0 + xv1[k + 1] * wk1;
      a1 += xv0[k + 2] * wk0 + xv1[k + 2] * wk1;
    }
  }
  float sc = g[c] * rsqrtf(vr[c] + EPS);
  float sh = bta[c] - mn[c] * sc;
  a0 = a0 * sc + sh; a1 = a1 * sc + sh;
  a0 = a0 >= 0.f ? a0 : 0.01f * a0;
  a1 = a1 >= 0.f ? a1 : 0.01f * a1;
  out1[((size_t)b * 32 + c) * 2047 + t] = fmaxf(a0, a1);
}

// ---------------- Weight pre-transpose: w[oc][ic][k] -> wTg[(ci*3+k)*OC + oc] ----------------
template<int IC, int OC>
__global__ __launch_bounds__(256) void kWT(const float* __restrict__ w, float* __restrict__ wTg) {
  int idx = blockIdx.x * 256 + threadIdx.x;
  if (idx < IC * 3 * OC) {
    int cc = idx % OC;
    int r = idx / OC;
    int ci = r / 3, k = r - 3 * ci;
    wTg[idx] = w[cc * IC * 3 + ci * 3 + k];
  }
}

// ---------------- Conv stage: conv(k=3,no pad) + bn + leaky + pool; SGPR weights ----------------
// 512 threads = 8 waves; lane = t offset, wave = channel group of NC=OC/8.
template<int IC, int OC, int LIN, int LOUT, int NC>
__global__ __launch_bounds__(512) void kConv(const float* __restrict__ in,
    const float* __restrict__ wTg, const float* __restrict__ g,
    const float* __restrict__ bta, const float* __restrict__ mn,
    const float* __restrict__ vr, float* __restrict__ out) {
  constexpr int ISTR = 132;
  __shared__ float in_tile[IC * ISTR];
  int tid = threadIdx.x;
  int lane = tid & 63;
  int wvu = __builtin_amdgcn_readfirstlane(tid >> 6);  // scalarize wave id
  int b = blockIdx.z;
  int t0 = blockIdx.x * 64;
  {
    int r = tid >> 3, j = tid & 7;
    if (r < IC) {
      const float* src = in + ((size_t)b * IC + r) * LIN + 2 * t0;
      for (int p = j; p < 130; p += 8) {
        int gp = 2 * t0 + p;
        in_tile[r * ISTR + p] = (gp < LIN) ? src[p] : 0.f;
      }
    }
  }
  __syncthreads();
  float accA[NC], accB[NC];
#pragma unroll
  for (int i = 0; i < NC; i++) { accA[i] = 0.f; accB[i] = 0.f; }
  int c_base = wvu * NC;
  for (int ci = 0; ci < IC; ci++) {
    const float* ip = in_tile + ci * ISTR + 2 * lane;
    float x0 = ip[0], x1 = ip[1], x2 = ip[2], x3 = ip[3];
    const float* wr = wTg + ci * 3 * OC + c_base;  // wave-uniform -> s_load
#pragma unroll
    for (int cc = 0; cc < NC; cc++) {
      float wa = wr[cc], wb = wr[OC + cc], wc = wr[2 * OC + cc];
      accA[cc] += x0 * wa + x1 * wb + x2 * wc;
      accB[cc] += x1 * wa + x2 * wb + x3 * wc;
    }
  }
  int t = t0 + lane;
  if (t < LOUT) {
#pragma unroll
    for (int i = 0; i < NC; i++) {
      int cc = c_base + i;
      float sc = g[cc] * rsqrtf(vr[cc] + EPS);
      float sh = bta[cc] - mn[cc] * sc;
      float a = accA[i] * sc + sh, bb = accB[i] * sc + sh;
      a = a >= 0.f ? a : 0.01f * a;
      bb = bb >= 0.f ? bb : 0.01f * bb;
      out[((size_t)b * OC + cc) * LOUT + t] = fmaxf(a, bb);
    }
  }
}

// ---------------- LN over channels (transpose) -> xn ; also capture e_last (t=509) ----------------
__global__ __launch_bounds__(256) void kLN1(const float* __restrict__ h3,
    const float* __restrict__ lnw, float* __restrict__ xn, float* __restrict__ elast) {
  __shared__ float tile[128 * 65];
  __shared__ float smu[64], srs[64];
  int tid = threadIdx.x;
  int b = blockIdx.z;
  int t0 = blockIdx.x * 64;
  {
    int tt = tid & 63, c0 = tid >> 6;
    for (int it = 0; it < 32; it++) {
      int c = c0 + it * 4;
      int t = t0 + tt;
      tile[c * 65 + tt] = (t < 510) ? h3[((size_t)b * 128 + c) * 510 + t] : 0.f;
    }
  }
  __syncthreads();
  {
    int tl = tid >> 2, q = tid & 3;
    float s1 = 0.f, s2 = 0.f;
    for (int j = 0; j < 32; j++) {
      float v = tile[(q * 32 + j) * 65 + tl];
      s1 += v; s2 += v * v;
    }
    s1 += __shfl_xor(s1, 1); s2 += __shfl_xor(s2, 1);
    s1 += __shfl_xor(s1, 2); s2 += __shfl_xor(s2, 2);
    if (q == 0) {
      float mu = s1 * (1.f / 128.f);
      float var = s2 * (1.f / 128.f) - mu * mu;
      smu[tl] = mu; srs[tl] = rsqrtf(var + EPS);
    }
  }
  __syncthreads();
  {
    int c = tid & 127, th = tid >> 7;
    for (int tt = th; tt < 64; tt += 2) {
      int t = t0 + tt;
      if (t < 510) {
        float v = tile[c * 65 + tt];
        xn[((size_t)b * 510 + t) * 128 + c] = (v - smu[tt]) * srs[tt] * lnw[c];
        if (t == 509) elast[b * 128 + c] = v;
      }
    }
  }
}

// ---------------- Fused depthwise-conv+SiLU + gate input-projections ----------------
// Per block: one (b,h). Tiles of 32 timesteps; xcv computed on the fly from xn slice.
// gx[s][bh][j] bf16, j = l*2+slot: slot0 = pre(i/f) from xcv, slot1 = pre(z/o) from xn.
__global__ __launch_bounds__(256) void kGx(const float* __restrict__ xn,
    const float* __restrict__ cw, const float* __restrict__ cb,
    const float* __restrict__ wi, const float* __restrict__ wf,
    const float* __restrict__ wz, const float* __restrict__ wo,
    const float* __restrict__ rb, __hip_bfloat16* __restrict__ gx) {
  __shared__ float lnb[34 * 32];  // xn rows s0-2 .. s0+31, channel slice
  __shared__ float cvb[32 * 32];  // xcv rows s0 .. s0+31
  int bh = blockIdx.x; int b = bh >> 2, h = bh & 3;
  int t = threadIdx.x;
  // projection mapping
  int j = t & 127, slot = j & 1, l = j >> 1;
  int halfg = l >> 5, e = l & 31;
  int sOff = t >> 7;  // 0 or 1
  const float* wp = (slot == 0) ? (halfg ? wf : wi) : (halfg ? wo : wz);
  wp += h * 1024 + e;
  float W[32];
#pragma unroll
  for (int d = 0; d < 32; d++) W[d] = wp[d * 32];
  float bias = rb[(slot * 2 + halfg) * 128 + h * 32 + e];
  // loader / dwconv mapping
  int cd = t & 31;
  float cw0 = cw[(h * 32 + cd) * 3], cw1 = cw[(h * 32 + cd) * 3 + 1], cw2 = cw[(h * 32 + cd) * 3 + 2];
  float cbv = cb[h * 32 + cd];
  const float* xb = xn + ((size_t)b * 510) * 128 + h * 32;
  for (int s0 = 0; s0 < 510; s0 += 32) {
    __syncthreads();
    for (int r = t >> 5; r < 34; r += 8) {
      int gs = s0 - 2 + r;
      lnb[r * 32 + cd] = (gs >= 0 && gs < 510) ? xb[(size_t)gs * 128 + cd] : 0.f;
    }
    __syncthreads();
    for (int r = t >> 5; r < 32; r += 8) {
      float acc = cbv + cw0 * lnb[r * 32 + cd] + cw1 * lnb[(r + 1) * 32 + cd]
                      + cw2 * lnb[(r + 2) * 32 + cd];
      cvb[r * 32 + cd] = acc * __builtin_amdgcn_rcpf(1.f + __expf(-acc));
    }
    __syncthreads();
    for (int sp = 0; sp < 32; sp += 2) {
      int r = sp + sOff;
      int s = s0 + r;
      if (s < 510) {
        const float* ib = (slot == 0) ? (cvb + r * 32) : (lnb + (r + 2) * 32);
        float q0 = 0.f, q1 = 0.f, q2 = 0.f, q3 = 0.f;
#pragma unroll
        for (int q = 0; q < 8; q++) {
          float4 v = *(const float4*)(ib + 4 * q);
          q0 += v.x * W[4 * q];
          q1 += v.y * W[4 * q + 1];
          q2 += v.z * W[4 * q + 2];
          q3 += v.w * W[4 * q + 3];
        }
        float acc = bias + (q0 + q1) + (q2 + q3);
        gx[((size_t)s * 1024 + bh) * 128 + j] = __float2bfloat16(acc);
      }
    }
  }
}

// ---------------- Lean sLSTM recurrence ----------------
// wave = (b,h). half = l>>5, e = l&31. half0: gates i(a1)/z(a2); half1: f(a1)/o(a2).
__global__ __launch_bounds__(64) void kRec(const unsigned int* __restrict__ gx,
    const float* __restrict__ rk, float* __restrict__ yf) {
  __shared__ float ybuf[64];
  int bh = blockIdx.x; int h = bh & 3;
  int l = threadIdx.x; int half = l >> 5; int e = l & 31;
  float R1[32], R2[32];
  int g1 = half, g2 = 2 + half;
  const float* r1p = rk + h * 4096 + g1 * 32 + e;
  const float* r2p = rk + h * 4096 + g2 * 32 + e;
#pragma unroll
  for (int d = 0; d < 32; d++) { R1[d] = r1p[d * 128]; R2[d] = r2p[d * 128]; }
  const unsigned int* gp = gx + (size_t)bh * 64 + l;  // per-s stride = 65536 uints
  unsigned int p0 = gp[0], p1 = gp[65536], p2 = gp[131072], p3 = gp[196608];
  float y = 0.f, cst = 0.f, nst = 0.f, mst = 0.f;
  ybuf[l] = 0.f;
  for (int s = 0; s < 510; s++) {
    unsigned int pc = p0; p0 = p1; p1 = p2; p2 = p3;
    if (s + 4 < 510) p3 = gp[(size_t)(s + 4) * 65536];
    float a1 = __uint_as_float(pc << 16);          // pre (i/f)
    float a2 = __uint_as_float(pc & 0xFFFF0000u);  // pre (z/o)
    float s10 = 0.f, s11 = 0.f, s12 = 0.f, s13 = 0.f;
    float s20 = 0.f, s21 = 0.f, s22 = 0.f, s23 = 0.f;
#pragma unroll
    for (int q = 0; q < 8; q++) {
      float4 yv = *(const float4*)(ybuf + 4 * q);
      s10 += yv.x * R1[4 * q];     s20 += yv.x * R2[4 * q];
      s11 += yv.y * R1[4 * q + 1]; s21 += yv.y * R2[4 * q + 1];
      s12 += yv.z * R1[4 * q + 2]; s22 += yv.z * R2[4 * q + 2];
      s13 += yv.w * R1[4 * q + 3]; s23 += yv.w * R2[4 * q + 3];
    }
    a1 += (s10 + s11) + (s12 + s13);
    a2 += (s20 + s21) + (s22 + s23);
    // fast transcendentals (native exp/log/rcp)
    float en = __expf(-fabsf(a1));
    float ls = fminf(a1, 0.f) - __logf(1.f + en);             // log-sigmoid(a1)
    float sg = __builtin_amdgcn_rcpf(1.f + __expf(-a2));      // sigmoid(a2)
    float tz = 1.f - 2.f * __builtin_amdgcn_rcpf(__expf(2.f * a2) + 1.f);  // tanh(a2)
    float lsf = __shfl_xor(ls, 32);   // half0 <- half1's logsig(fraw)
    float so  = __shfl_xor(sg, 32);   // half0 <- half1's sigmoid(oraw)
    float lf = mst + lsf;
    float mnew = fmaxf(a1, lf);       // a1 = iraw on half0
    float ig = __expf(a1 - mnew);
    float fg = __expf(lf - mnew);
    cst = fg * cst + ig * tz;
    nst = fg * nst + ig;
    mst = mnew;
    y = so * cst * __builtin_amdgcn_rcpf(nst);
    ybuf[l] = y;  // half0 -> slots 0..31 (valid); half1 -> dummy
  }
  if (half == 0) yf[(bh >> 2) * 128 + h * 32 + e] = y;
}

// ---------------- Tail for the last timestep only ----------------
__global__ __launch_bounds__(128) void kHead(const float* __restrict__ yf,
    const float* __restrict__ elast, const float* __restrict__ gnw,
    const float* __restrict__ ln2w, const float* __restrict__ upw,
    const float* __restrict__ dnw, const float* __restrict__ lnpw,
    const float* __restrict__ fcw, const float* __restrict__ fcb,
    float* __restrict__ outp) {
  int c = threadIdx.x; int b = blockIdx.x;
  __shared__ float sred[4];
  __shared__ float sx[128];
  __shared__ float sup[384];
  __shared__ float shh[192];
  float yv = yf[b * 128 + c];
  float s1 = yv, s2 = yv * yv;
#pragma unroll
  for (int m = 1; m <= 16; m <<= 1) { s1 += __shfl_xor(s1, m); s2 += __shfl_xor(s2, m); }
  float mu = s1 * (1.f / 32.f);
  float var = s2 * (1.f / 32.f) - mu * mu;
  float yn = (yv - mu) * rsqrtf(var + EPS) * gnw[c];
  float el = elast[b * 128 + c] + yn;
  auto ln128 = [&](float v, const float* w) -> float {
    float a = v, a2 = v * v;
#pragma unroll
    for (int m = 1; m <= 32; m <<= 1) { a += __shfl_xor(a, m); a2 += __shfl_xor(a2, m); }
    int wv = c >> 6;
    if ((c & 63) == 0) { sred[wv * 2] = a; sred[wv * 2 + 1] = a2; }
    __syncthreads();
    float t1 = sred[0] + sred[2], t2 = sred[1] + sred[3];
    __syncthreads();
    float mm = t1 * (1.f / 128.f);
    float vv = t2 * (1.f / 128.f) - mm * mm;
    return (v - mm) * rsqrtf(vv + EPS) * w[c];
  };
  float xn2 = ln128(el, ln2w);
  sx[c] = xn2;
  __syncthreads();
#pragma unroll
  for (int jj = 0; jj < 3; jj++) {
    int j = c + jj * 128;
    float acc = 0.f;
    for (int k = 0; k < 128; k++) acc += sx[k] * upw[k * 384 + j];
    sup[j] = acc;
  }
  __syncthreads();
  {
    float u = sup[c]; float mg = sup[192 + c];
    shh[c] = 0.5f * u * (1.f + erff(u * 0.70710678118654752f)) * mg;
    if (c < 64) {
      float u2 = sup[128 + c]; float m2 = sup[320 + c];
      shh[128 + c] = 0.5f * u2 * (1.f + erff(u2 * 0.70710678118654752f)) * m2;
    }
  }
  __syncthreads();
  float acc = 0.f;
  for (int f = 0; f < 192; f++) acc += shh[f] * dnw[f * 128 + c];
  float e2 = el + acc;
  float e3 = ln128(e2, lnpw);
  sx[c] = e3;
  __syncthreads();
  if (c < 5) {
    float a = fcb[c];
    for (int k = 0; k < 128; k++) a += sx[k] * fcw[k * 5 + c];
    outp[b * 5 + c] = a;
  }
}

extern "C" void kernel_launch(void* const* d_in, const int* in_sizes, int n_in,
                              void* d_out, int out_size, void* d_ws, size_t ws_size,
                              hipStream_t stream) {
  const float* x    = (const float*)d_in[0];
  const float* w1a  = (const float*)d_in[1];
  const float* w1b  = (const float*)d_in[2];
  const float* bn1g = (const float*)d_in[3];
  const float* bn1b = (const float*)d_in[4];
  const float* bn1m = (const float*)d_in[5];
  const float* bn1v = (const float*)d_in[6];
  const float* w2   = (const float*)d_in[7];
  const float* bn2g = (const float*)d_in[8];
  const float* bn2b = (const float*)d_in[9];
  const float* bn2m = (const float*)d_in[10];
  const float* bn2v = (const float*)d_in[11];
  const float* w3   = (const float*)d_in[12];
  const float* bn3g = (const float*)d_in[13];
  const float* bn3b = (const float*)d_in[14];
  const float* bn3m = (const float*)d_in[15];
  const float* bn3v = (const float*)d_in[16];
  const float* ln1w = (const float*)d_in[17];
  const float* cw   = (const float*)d_in[18];
  const float* cb   = (const float*)d_in[19];
  const float* wi   = (const float*)d_in[20];
  const float* wf   = (const float*)d_in[21];
  const float* wz   = (const float*)d_in[22];
  const float* wo   = (const float*)d_in[23];
  const float* rk   = (const float*)d_in[24];
  const float* rb   = (const float*)d_in[25];
  const float* gnw  = (const float*)d_in[26];
  const float* ln2w = (const float*)d_in[27];
  const float* upw  = (const float*)d_in[28];
  const float* dnw  = (const float*)d_in[29];
  const float* lnpw = (const float*)d_in[30];
  const float* fcw  = (const float*)d_in[31];
  const float* fcb  = (const float*)d_in[32];
  float* outp = (float*)d_out;

  char* ws = (char*)d_ws;
  float* buf1  = (float*)ws;                                        // 64 MiB
  float* buf2  = (float*)(ws + ((size_t)64 << 20));                 // 64 MiB
  __hip_bfloat16* gxb = (__hip_bfloat16*)(ws + ((size_t)128 << 20)); // 133.7 MB
  float* elast = (float*)(ws + ((size_t)258 << 20));
  float* yfin  = (float*)(ws + ((size_t)259 << 20));
  float* wtg2  = (float*)(ws + ((size_t)260 << 20));                // 24 KB
  float* wtg3  = (float*)(ws + ((size_t)260 << 20) + (1 << 20));    // 96 KB

  float* out1 = buf1;  // [256][32][2047]
  float* out2 = buf2;  // [256][64][1022]
  float* h3   = buf1;  // [256][128][510]
  float* xnb  = buf2;  // [256][510][128]

  kWT<32, 64><<<dim3(24), 256, 0, stream>>>(w2, wtg2);
  kWT<64, 128><<<dim3(96), 256, 0, stream>>>(w3, wtg3);
  kA<<<dim3(8, 32, 256), 256, 0, stream>>>(x, w1a, w1b, bn1g, bn1b, bn1m, bn1v, out1);
  kConv<32, 64, 2047, 1022, 8><<<dim3(16, 1, 256), 512, 0, stream>>>(
      out1, wtg2, bn2g, bn2b, bn2m, bn2v, out2);
  kConv<64, 128, 1022, 510, 16><<<dim3(8, 1, 256), 512, 0, stream>>>(
      out2, wtg3, bn3g, bn3b, bn3m, bn3v, h3);
  kLN1<<<dim3(8, 1, 256), 256, 0, stream>>>(h3, ln1w, xnb, elast);
  kGx<<<dim3(1024), 256, 0, stream>>>(xnb, cw, cb, wi, wf, wz, wo, rb, gxb);
  kRec<<<dim3(1024), 64, 0, stream>>>((const unsigned int*)gxb, rk, yfin);
  kHead<<<dim3(256), 128, 0, stream>>>(yfin, elast, gnw, ln2w, upw, dnw, lnpw, fcw, fcb, outp);
}

// Round 4
// 758.105 us; speedup vs baseline: 2.3377x; 1.2265x over previous
//
#include <hip/hip_runtime.h>
#include <hip/hip_bf16.h>
#include <math.h>

#define EPS 1e-5f

typedef __attribute__((ext_vector_type(8))) short short8;
typedef __attribute__((ext_vector_type(4))) float f32x4;

// ---------------- Kernel A: conv1 (two branches, concat) + bn1 + leaky + pool ----------------
// x: [256][4096][2] -> out1 bf16 [256][2047][32]  (position-major for conv2 MFMA staging)
__global__ __launch_bounds__(256) void kA(const float* __restrict__ x,
    const float* __restrict__ w1a, const float* __restrict__ w1b,
    const float* __restrict__ g, const float* __restrict__ bta,
    const float* __restrict__ mn, const float* __restrict__ vr,
    __hip_bfloat16* __restrict__ out1) {
  int c = threadIdx.x & 31;
  int t = blockIdx.x * 8 + (threadIdx.x >> 5);
  int b = blockIdx.z;
  if (t >= 2047) return;
  float xv0[5], xv1[5];
  const float* xb = x + (size_t)b * 4096 * 2;
#pragma unroll
  for (int j = 0; j < 5; j++) {
    int l = 2 * t - 1 + j;
    if (l >= 0 && l < 4096) { xv0[j] = xb[l * 2]; xv1[j] = xb[l * 2 + 1]; }
    else { xv0[j] = 0.f; xv1[j] = 0.f; }
  }
  float a0 = 0.f, a1 = 0.f;
  if (c < 16) {
#pragma unroll
    for (int k = 0; k < 4; k++) {
      float wk0 = w1a[c * 8 + k];
      float wk1 = w1a[c * 8 + 4 + k];
      a0 += xv0[k] * wk0 + xv1[k] * wk1;
      a1 += xv0[k + 1] * wk0 + xv1[k + 1] * wk1;
    }
  } else {
    int cc = c - 16;
#pragma unroll
    for (int k = 0; k < 2; k++) {
      float wk0 = w1b[cc * 4 + k];
      float wk1 = w1b[cc * 4 + 2 + k];
      a0 += xv0[k + 1] * wk0 + xv1[k + 1] * wk1;
      a1 += xv0[k + 2] * wk0 + xv1[k + 2] * wk1;
    }
  }
  float sc = g[c] * rsqrtf(vr[c] + EPS);
  float sh = bta[c] - mn[c] * sc;
  a0 = a0 * sc + sh; a1 = a1 * sc + sh;
  a0 = a0 >= 0.f ? a0 : 0.01f * a0;
  a1 = a1 >= 0.f ? a1 : 0.01f * a1;
  out1[((size_t)b * 2047 + t) * 32 + c] = __float2bfloat16(fmaxf(a0, a1));
}

// ---------------- Weight transform: w[oc][ci][k] fp32 -> B^T bf16 [oc][k_idx=k*IC+ci], padded ----------------
template<int IC, int OC, int BP>
__global__ __launch_bounds__(256) void kWTB(const float* __restrict__ w,
    __hip_bfloat16* __restrict__ out) {
  int idx = blockIdx.x * 256 + threadIdx.x;
  if (idx >= OC * BP) return;
  int oc = idx / BP, kp = idx % BP;
  float v = 0.f;
  if (kp < IC * 3) { int k = kp / IC, ci = kp % IC; v = w[oc * IC * 3 + ci * 3 + k]; }
  out[idx] = __float2bfloat16(v);
}

// ---------------- MFMA conv stage: conv(k=3) + bn + leaky + pool ----------------
// in bf16 [b][p][IC]; out: OBF? bf16 [b][t][OC] : fp32 [b][t][OC].
// Block: 512 thr = 8 waves; chunk of 128 pre-pool positions; wave w -> m-tile rows w*16..+15.
// AP = A-row pad (bf16 elems), BP = B-row pad. Stride bytes % 128 == 16 -> 2-way max (free).
template<int IC, int OC, int LIN, int LOUT, int AP, int BP, bool OBF>
__global__ __launch_bounds__(512) void kConvM(const __hip_bfloat16* __restrict__ in,
    const __hip_bfloat16* __restrict__ Bw, const float* __restrict__ g,
    const float* __restrict__ bta, const float* __restrict__ mn,
    const float* __restrict__ vr, void* __restrict__ outv) {
  constexpr int KSTEPS = (IC * 3) / 32;
  constexpr int OCT = OC / 16;
  __shared__ short sA[130 * AP];
  __shared__ short sB[OC * BP];
  int tid = threadIdx.x;
  int chunk = blockIdx.x, b = blockIdx.z;
  int p0 = chunk * 128;
  // stage B (whole weight matrix, padded layout already)
  {
    const unsigned int* src = (const unsigned int*)Bw;
    unsigned int* dst = (unsigned int*)sB;
    for (int i = tid; i < OC * BP / 2; i += 512) dst[i] = src[i];
  }
  // stage A: 130 rows x IC bf16, 16B per thread-slot
  {
    constexpr int TPR = IC / 8;
    int q = tid % TPR;
    for (int r = tid / TPR; r < 130; r += 512 / TPR) {
      int gp = p0 + r;
      uint4 val = {0u, 0u, 0u, 0u};
      if (gp < LIN) val = *(const uint4*)((const short*)in + ((size_t)b * LIN + gp) * IC + q * 8);
      *(uint4*)(sA + r * AP + q * 8) = val;
    }
  }
  __syncthreads();
  int lane = tid & 63, w = tid >> 6;
  int nrow = lane & 15, quad = lane >> 4;
  f32x4 acc[OCT];
#pragma unroll
  for (int i = 0; i < OCT; i++) acc[i] = (f32x4){0.f, 0.f, 0.f, 0.f};
  int mbase = w * 16;
#pragma unroll
  for (int kk = 0; kk < KSTEPS; kk++) {
    int k = (kk * 32) / IC;
    int ci0 = (kk * 32) % IC;
    short8 a = *(const short8*)(sA + (mbase + nrow + k) * AP + ci0 + quad * 8);
#pragma unroll
    for (int ot = 0; ot < OCT; ot++) {
      short8 bb = *(const short8*)(sB + (ot * 16 + nrow) * BP + kk * 32 + quad * 8);
      acc[ot] = __builtin_amdgcn_mfma_f32_16x16x32_bf16(a, bb, acc[ot], 0, 0, 0);
    }
  }
  // epilogue: bn + leaky + pool (rows quad*4+reg are in-lane; pairs (0,1),(2,3) pool)
  int gm0 = p0 + mbase + quad * 4;
#pragma unroll
  for (int ot = 0; ot < OCT; ot++) {
    int oc = ot * 16 + nrow;
    float sc = g[oc] * rsqrtf(vr[oc] + EPS);
    float sh = bta[oc] - mn[oc] * sc;
    float v0 = acc[ot][0] * sc + sh, v1 = acc[ot][1] * sc + sh;
    float v2 = acc[ot][2] * sc + sh, v3 = acc[ot][3] * sc + sh;
    v0 = v0 >= 0.f ? v0 : 0.01f * v0;
    v1 = v1 >= 0.f ? v1 : 0.01f * v1;
    v2 = v2 >= 0.f ? v2 : 0.01f * v2;
    v3 = v3 >= 0.f ? v3 : 0.01f * v3;
    float pA = fmaxf(v0, v1), pB = fmaxf(v2, v3);
    int t0 = gm0 >> 1, t1 = t0 + 1;
    if (OBF) {
      __hip_bfloat16* o = (__hip_bfloat16*)outv;
      if (t0 < LOUT) o[((size_t)b * LOUT + t0) * OC + oc] = __float2bfloat16(pA);
      if (t1 < LOUT) o[((size_t)b * LOUT + t1) * OC + oc] = __float2bfloat16(pB);
    } else {
      float* o = (float*)outv;
      if (t0 < LOUT) o[((size_t)b * LOUT + t0) * OC + oc] = pA;
      if (t1 < LOUT) o[((size_t)b * LOUT + t1) * OC + oc] = pB;
    }
  }
}

// ---------------- Row-wise LN over channels -> xn fp32 [b][t][128] ; capture e_last(t=509) ----------------
__global__ __launch_bounds__(256) void kLN1b(const float* __restrict__ h3,
    const float* __restrict__ lnw, float* __restrict__ xn, float* __restrict__ elast) {
  int lane = threadIdx.x & 63;
  int t = blockIdx.x * 4 + (threadIdx.x >> 6);
  int b = blockIdx.z;
  if (t >= 510) return;
  const float* row = h3 + ((size_t)b * 510 + t) * 128;
  float2 v = *(const float2*)(row + lane * 2);
  float s1 = v.x + v.y, s2 = v.x * v.x + v.y * v.y;
#pragma unroll
  for (int m = 1; m <= 32; m <<= 1) { s1 += __shfl_xor(s1, m); s2 += __shfl_xor(s2, m); }
  float mu = s1 * (1.f / 128.f);
  float rs = rsqrtf(s2 * (1.f / 128.f) - mu * mu + EPS);
  float2 o;
  o.x = (v.x - mu) * rs * lnw[2 * lane];
  o.y = (v.y - mu) * rs * lnw[2 * lane + 1];
  *(float2*)(xn + ((size_t)b * 510 + t) * 128 + lane * 2) = o;
  if (t == 509) *(float2*)(elast + b * 128 + lane * 2) = v;
}

// ---------------- Fused depthwise-conv+SiLU + gate input-projections ----------------
__global__ __launch_bounds__(256) void kGx(const float* __restrict__ xn,
    const float* __restrict__ cw, const float* __restrict__ cb,
    const float* __restrict__ wi, const float* __restrict__ wf,
    const float* __restrict__ wz, const float* __restrict__ wo,
    const float* __restrict__ rb, __hip_bfloat16* __restrict__ gx) {
  __shared__ float lnb[34 * 32];
  __shared__ float cvb[32 * 32];
  int bh = blockIdx.x; int b = bh >> 2, h = bh & 3;
  int t = threadIdx.x;
  int j = t & 127, slot = j & 1, l = j >> 1;
  int halfg = l >> 5, e = l & 31;
  int sOff = t >> 7;
  const float* wp = (slot == 0) ? (halfg ? wf : wi) : (halfg ? wo : wz);
  wp += h * 1024 + e;
  float W[32];
#pragma unroll
  for (int d = 0; d < 32; d++) W[d] = wp[d * 32];
  float bias = rb[(slot * 2 + halfg) * 128 + h * 32 + e];
  int cd = t & 31;
  float cw0 = cw[(h * 32 + cd) * 3], cw1 = cw[(h * 32 + cd) * 3 + 1], cw2 = cw[(h * 32 + cd) * 3 + 2];
  float cbv = cb[h * 32 + cd];
  const float* xb = xn + ((size_t)b * 510) * 128 + h * 32;
  for (int s0 = 0; s0 < 510; s0 += 32) {
    __syncthreads();
    for (int r = t >> 5; r < 34; r += 8) {
      int gs = s0 - 2 + r;
      lnb[r * 32 + cd] = (gs >= 0 && gs < 510) ? xb[(size_t)gs * 128 + cd] : 0.f;
    }
    __syncthreads();
    for (int r = t >> 5; r < 32; r += 8) {
      float acc = cbv + cw0 * lnb[r * 32 + cd] + cw1 * lnb[(r + 1) * 32 + cd]
                      + cw2 * lnb[(r + 2) * 32 + cd];
      cvb[r * 32 + cd] = acc * __builtin_amdgcn_rcpf(1.f + __expf(-acc));
    }
    __syncthreads();
    for (int sp = 0; sp < 32; sp += 2) {
      int r = sp + sOff;
      int s = s0 + r;
      if (s < 510) {
        const float* ib = (slot == 0) ? (cvb + r * 32) : (lnb + (r + 2) * 32);
        float q0 = 0.f, q1 = 0.f, q2 = 0.f, q3 = 0.f;
#pragma unroll
        for (int q = 0; q < 8; q++) {
          float4 v = *(const float4*)(ib + 4 * q);
          q0 += v.x * W[4 * q];
          q1 += v.y * W[4 * q + 1];
          q2 += v.z * W[4 * q + 2];
          q3 += v.w * W[4 * q + 3];
        }
        float acc = bias + (q0 + q1) + (q2 + q3);
        gx[((size_t)s * 1024 + bh) * 128 + j] = __float2bfloat16(acc);
      }
    }
  }
}

// ---------------- Lean sLSTM recurrence ----------------
__global__ __launch_bounds__(64) void kRec(const unsigned int* __restrict__ gx,
    const float* __restrict__ rk, float* __restrict__ yf) {
  __shared__ float ybuf[64];
  int bh = blockIdx.x; int h = bh & 3;
  int l = threadIdx.x; int half = l >> 5; int e = l & 31;
  float R1[32], R2[32];
  int g1 = half, g2 = 2 + half;
  const float* r1p = rk + h * 4096 + g1 * 32 + e;
  const float* r2p = rk + h * 4096 + g2 * 32 + e;
#pragma unroll
  for (int d = 0; d < 32; d++) { R1[d] = r1p[d * 128]; R2[d] = r2p[d * 128]; }
  const unsigned int* gp = gx + (size_t)bh * 64 + l;
  unsigned int p0 = gp[0], p1 = gp[65536], p2 = gp[131072], p3 = gp[196608];
  float y = 0.f, cst = 0.f, nst = 0.f, mst = 0.f;
  ybuf[l] = 0.f;
  for (int s = 0; s < 510; s++) {
    unsigned int pc = p0; p0 = p1; p1 = p2; p2 = p3;
    if (s + 4 < 510) p3 = gp[(size_t)(s + 4) * 65536];
    float a1 = __uint_as_float(pc << 16);
    float a2 = __uint_as_float(pc & 0xFFFF0000u);
    float s10 = 0.f, s11 = 0.f, s12 = 0.f, s13 = 0.f;
    float s20 = 0.f, s21 = 0.f, s22 = 0.f, s23 = 0.f;
#pragma unroll
    for (int q = 0; q < 8; q++) {
      float4 yv = *(const float4*)(ybuf + 4 * q);
      s10 += yv.x * R1[4 * q];     s20 += yv.x * R2[4 * q];
      s11 += yv.y * R1[4 * q + 1]; s21 += yv.y * R2[4 * q + 1];
      s12 += yv.z * R1[4 * q + 2]; s22 += yv.z * R2[4 * q + 2];
      s13 += yv.w * R1[4 * q + 3]; s23 += yv.w * R2[4 * q + 3];
    }
    a1 += (s10 + s11) + (s12 + s13);
    a2 += (s20 + s21) + (s22 + s23);
    float en = __expf(-fabsf(a1));
    float ls = fminf(a1, 0.f) - __logf(1.f + en);
    float sg = __builtin_amdgcn_rcpf(1.f + __expf(-a2));
    float tz = 1.f - 2.f * __builtin_amdgcn_rcpf(__expf(2.f * a2) + 1.f);
    float lsf = __shfl_xor(ls, 32);
    float so  = __shfl_xor(sg, 32);
    float lf = mst + lsf;
    float mnew = fmaxf(a1, lf);
    float ig = __expf(a1 - mnew);
    float fg = __expf(lf - mnew);
    cst = fg * cst + ig * tz;
    nst = fg * nst + ig;
    mst = mnew;
    y = so * cst * __builtin_amdgcn_rcpf(nst);
    ybuf[l] = y;
  }
  if (half == 0) yf[(bh >> 2) * 128 + h * 32 + e] = y;
}

// ---------------- Tail for the last timestep only ----------------
__global__ __launch_bounds__(128) void kHead(const float* __restrict__ yf,
    const float* __restrict__ elast, const float* __restrict__ gnw,
    const float* __restrict__ ln2w, const float* __restrict__ upw,
    const float* __restrict__ dnw, const float* __restrict__ lnpw,
    const float* __restrict__ fcw, const float* __restrict__ fcb,
    float* __restrict__ outp) {
  int c = threadIdx.x; int b = blockIdx.x;
  __shared__ float sred[4];
  __shared__ float sx[128];
  __shared__ float sup[384];
  __shared__ float shh[192];
  float yv = yf[b * 128 + c];
  float s1 = yv, s2 = yv * yv;
#pragma unroll
  for (int m = 1; m <= 16; m <<= 1) { s1 += __shfl_xor(s1, m); s2 += __shfl_xor(s2, m); }
  float mu = s1 * (1.f / 32.f);
  float var = s2 * (1.f / 32.f) - mu * mu;
  float yn = (yv - mu) * rsqrtf(var + EPS) * gnw[c];
  float el = elast[b * 128 + c] + yn;
  auto ln128 = [&](float v, const float* w) -> float {
    float a = v, a2 = v * v;
#pragma unroll
    for (int m = 1; m <= 32; m <<= 1) { a += __shfl_xor(a, m); a2 += __shfl_xor(a2, m); }
    int wv = c >> 6;
    if ((c & 63) == 0) { sred[wv * 2] = a; sred[wv * 2 + 1] = a2; }
    __syncthreads();
    float t1 = sred[0] + sred[2], t2 = sred[1] + sred[3];
    __syncthreads();
    float mm = t1 * (1.f / 128.f);
    float vv = t2 * (1.f / 128.f) - mm * mm;
    return (v - mm) * rsqrtf(vv + EPS) * w[c];
  };
  float xn2 = ln128(el, ln2w);
  sx[c] = xn2;
  __syncthreads();
#pragma unroll
  for (int jj = 0; jj < 3; jj++) {
    int j = c + jj * 128;
    float acc = 0.f;
    for (int k = 0; k < 128; k++) acc += sx[k] * upw[k * 384 + j];
    sup[j] = acc;
  }
  __syncthreads();
  {
    float u = sup[c]; float mg = sup[192 + c];
    shh[c] = 0.5f * u * (1.f + erff(u * 0.70710678118654752f)) * mg;
    if (c < 64) {
      float u2 = sup[128 + c]; float m2 = sup[320 + c];
      shh[128 + c] = 0.5f * u2 * (1.f + erff(u2 * 0.70710678118654752f)) * m2;
    }
  }
  __syncthreads();
  float acc = 0.f;
  for (int f = 0; f < 192; f++) acc += shh[f] * dnw[f * 128 + c];
  float e2 = el + acc;
  float e3 = ln128(e2, lnpw);
  sx[c] = e3;
  __syncthreads();
  if (c < 5) {
    float a = fcb[c];
    for (int k = 0; k < 128; k++) a += sx[k] * fcw[k * 5 + c];
    outp[b * 5 + c] = a;
  }
}

extern "C" void kernel_launch(void* const* d_in, const int* in_sizes, int n_in,
                              void* d_out, int out_size, void* d_ws, size_t ws_size,
                              hipStream_t stream) {
  const float* x    = (const float*)d_in[0];
  const float* w1a  = (const float*)d_in[1];
  const float* w1b  = (const float*)d_in[2];
  const float* bn1g = (const float*)d_in[3];
  const float* bn1b = (const float*)d_in[4];
  const float* bn1m = (const float*)d_in[5];
  const float* bn1v = (const float*)d_in[6];
  const float* w2   = (const float*)d_in[7];
  const float* bn2g = (const float*)d_in[8];
  const float* bn2b = (const float*)d_in[9];
  const float* bn2m = (const float*)d_in[10];
  const float* bn2v = (const float*)d_in[11];
  const float* w3   = (const float*)d_in[12];
  const float* bn3g = (const float*)d_in[13];
  const float* bn3b = (const float*)d_in[14];
  const float* bn3m = (const float*)d_in[15];
  const float* bn3v = (const float*)d_in[16];
  const float* ln1w = (const float*)d_in[17];
  const float* cw   = (const float*)d_in[18];
  const float* cb   = (const float*)d_in[19];
  const float* wi   = (const float*)d_in[20];
  const float* wf   = (const float*)d_in[21];
  const float* wz   = (const float*)d_in[22];
  const float* wo   = (const float*)d_in[23];
  const float* rk   = (const float*)d_in[24];
  const float* rb   = (const float*)d_in[25];
  const float* gnw  = (const float*)d_in[26];
  const float* ln2w = (const float*)d_in[27];
  const float* upw  = (const float*)d_in[28];
  const float* dnw  = (const float*)d_in[29];
  const float* lnpw = (const float*)d_in[30];
  const float* fcw  = (const float*)d_in[31];
  const float* fcb  = (const float*)d_in[32];
  float* outp = (float*)d_out;

  char* ws = (char*)d_ws;
  // buf1: kA-out bf16 [256][2047][32] (33.5MB) then h3 fp32 [256][510][128] (66.85MB)
  // buf2: conv2-out bf16 [256][1022][64] (33.5MB) then xn fp32 (66.85MB)
  __hip_bfloat16* out1 = (__hip_bfloat16*)ws;
  float* h3 = (float*)ws;
  __hip_bfloat16* out2 = (__hip_bfloat16*)(ws + ((size_t)64 << 20));
  float* xnb = (float*)(ws + ((size_t)64 << 20));
  __hip_bfloat16* gxb = (__hip_bfloat16*)(ws + ((size_t)128 << 20));  // 133.7MB
  float* elast = (float*)(ws + ((size_t)258 << 20));
  float* yfin  = (float*)(ws + ((size_t)259 << 20));
  __hip_bfloat16* wtg2b = (__hip_bfloat16*)(ws + ((size_t)260 << 20));            // 64*104*2 = 13.3KB
  __hip_bfloat16* wtg3b = (__hip_bfloat16*)(ws + ((size_t)260 << 20) + (1 << 20)); // 128*200*2 = 51.2KB

  kWTB<32, 64, 104><<<dim3(26), 256, 0, stream>>>(w2, wtg2b);
  kWTB<64, 128, 200><<<dim3(100), 256, 0, stream>>>(w3, wtg3b);
  kA<<<dim3(256, 1, 256), 256, 0, stream>>>(x, w1a, w1b, bn1g, bn1b, bn1m, bn1v, out1);
  // conv2: IC=32 OC=64 LIN=2047 LOUT=1022, AP=40 (80B rows), BP=104 (208B rows), bf16 out
  kConvM<32, 64, 2047, 1022, 40, 104, true><<<dim3(16, 1, 256), 512, 0, stream>>>(
      out1, wtg2b, bn2g, bn2b, bn2m, bn2v, (void*)out2);
  // conv3: IC=64 OC=128 LIN=1022 LOUT=510, AP=72 (144B rows), BP=200 (400B rows), fp32 out
  kConvM<64, 128, 1022, 510, 72, 200, false><<<dim3(8, 1, 256), 512, 0, stream>>>(
      out2, wtg3b, bn3g, bn3b, bn3m, bn3v, (void*)h3);
  kLN1b<<<dim3(128, 1, 256), 256, 0, stream>>>(h3, ln1w, xnb, elast);
  kGx<<<dim3(1024), 256, 0, stream>>>(xnb, cw, cb, wi, wf, wz, wo, rb, gxb);
  kRec<<<dim3(1024), 64, 0, stream>>>((const unsigned int*)gxb, rk, yfin);
  kHead<<<dim3(256), 128, 0, stream>>>(yfin, elast, gnw, ln2w, upw, dnw, lnpw, fcw, fcb, outp);
}

// Round 5
// 669.775 us; speedup vs baseline: 2.6460x; 1.1319x over previous
//
#include <hip/hip_runtime.h>
#include <hip/hip_bf16.h>
#include <math.h>

#define EPS 1e-5f

typedef __attribute__((ext_vector_type(8))) short short8;
typedef __attribute__((ext_vector_type(4))) float f32x4;

static __device__ __forceinline__ short bf16s(float x) {
  __hip_bfloat16 t = __float2bfloat16(x);
  return *(short*)&t;
}

// ---------------- Kernel A: conv1 (two branches, concat) + bn1 + leaky + pool ----------------
// x: [256][4096][2] -> out1 bf16 [256][2047][32]
__global__ __launch_bounds__(256) void kA(const float* __restrict__ x,
    const float* __restrict__ w1a, const float* __restrict__ w1b,
    const float* __restrict__ g, const float* __restrict__ bta,
    const float* __restrict__ mn, const float* __restrict__ vr,
    __hip_bfloat16* __restrict__ out1) {
  int c = threadIdx.x & 31;
  int t = blockIdx.x * 8 + (threadIdx.x >> 5);
  int b = blockIdx.z;
  if (t >= 2047) return;
  float xv0[5], xv1[5];
  const float* xb = x + (size_t)b * 4096 * 2;
#pragma unroll
  for (int j = 0; j < 5; j++) {
    int l = 2 * t - 1 + j;
    if (l >= 0 && l < 4096) { xv0[j] = xb[l * 2]; xv1[j] = xb[l * 2 + 1]; }
    else { xv0[j] = 0.f; xv1[j] = 0.f; }
  }
  float a0 = 0.f, a1 = 0.f;
  if (c < 16) {
#pragma unroll
    for (int k = 0; k < 4; k++) {
      float wk0 = w1a[c * 8 + k];
      float wk1 = w1a[c * 8 + 4 + k];
      a0 += xv0[k] * wk0 + xv1[k] * wk1;
      a1 += xv0[k + 1] * wk0 + xv1[k + 1] * wk1;
    }
  } else {
    int cc = c - 16;
#pragma unroll
    for (int k = 0; k < 2; k++) {
      float wk0 = w1b[cc * 4 + k];
      float wk1 = w1b[cc * 4 + 2 + k];
      a0 += xv0[k + 1] * wk0 + xv1[k + 1] * wk1;
      a1 += xv0[k + 2] * wk0 + xv1[k + 2] * wk1;
    }
  }
  float sc = g[c] * rsqrtf(vr[c] + EPS);
  float sh = bta[c] - mn[c] * sc;
  a0 = a0 * sc + sh; a1 = a1 * sc + sh;
  a0 = a0 >= 0.f ? a0 : 0.01f * a0;
  a1 = a1 >= 0.f ? a1 : 0.01f * a1;
  out1[((size_t)b * 2047 + t) * 32 + c] = __float2bfloat16(fmaxf(a0, a1));
}

// ---------------- Combined weight transform for conv2+conv3: -> B^T bf16 padded ----------------
__global__ __launch_bounds__(256) void kWTB2(const float* __restrict__ w2,
    const float* __restrict__ w3, __hip_bfloat16* __restrict__ o2,
    __hip_bfloat16* __restrict__ o3) {
  int idx = blockIdx.x * 256 + threadIdx.x;
  if (idx < 64 * 104) {
    int oc = idx / 104, kp = idx % 104;
    float v = 0.f;
    if (kp < 96) { int k = kp >> 5, ci = kp & 31; v = w2[oc * 96 + ci * 3 + k]; }
    o2[idx] = __float2bfloat16(v);
  } else {
    int j = idx - 64 * 104;
    if (j < 128 * 200) {
      int oc = j / 200, kp = j % 200;
      float v = 0.f;
      if (kp < 192) { int k = kp >> 6, ci = kp & 63; v = w3[oc * 192 + ci * 3 + k]; }
      o3[j] = __float2bfloat16(v);
    }
  }
}

// ---------------- MFMA conv2: conv(k=3) + bn + leaky + pool -> bf16 [b][t][64] ----------------
template<int IC, int OC, int LIN, int LOUT, int AP, int BP>
__global__ __launch_bounds__(512) void kConvM(const __hip_bfloat16* __restrict__ in,
    const __hip_bfloat16* __restrict__ Bw, const float* __restrict__ g,
    const float* __restrict__ bta, const float* __restrict__ mn,
    const float* __restrict__ vr, __hip_bfloat16* __restrict__ out) {
  constexpr int KSTEPS = (IC * 3) / 32;
  constexpr int OCT = OC / 16;
  __shared__ short sA[130 * AP];
  __shared__ short sB[OC * BP];
  int tid = threadIdx.x;
  int b = blockIdx.z;
  int p0 = blockIdx.x * 128;
  {
    const unsigned int* src = (const unsigned int*)Bw;
    unsigned int* dst = (unsigned int*)sB;
    for (int i = tid; i < OC * BP / 2; i += 512) dst[i] = src[i];
  }
  {
    constexpr int TPR = IC / 8;
    int q = tid % TPR;
    for (int r = tid / TPR; r < 130; r += 512 / TPR) {
      int gp = p0 + r;
      uint4 val = {0u, 0u, 0u, 0u};
      if (gp < LIN) val = *(const uint4*)((const short*)in + ((size_t)b * LIN + gp) * IC + q * 8);
      *(uint4*)(sA + r * AP + q * 8) = val;
    }
  }
  __syncthreads();
  int lane = tid & 63, w = tid >> 6;
  int nrow = lane & 15, quad = lane >> 4;
  f32x4 acc[OCT];
#pragma unroll
  for (int i = 0; i < OCT; i++) acc[i] = (f32x4){0.f, 0.f, 0.f, 0.f};
  int mbase = w * 16;
#pragma unroll
  for (int kk = 0; kk < KSTEPS; kk++) {
    int k = (kk * 32) / IC;
    int ci0 = (kk * 32) % IC;
    short8 a = *(const short8*)(sA + (mbase + nrow + k) * AP + ci0 + quad * 8);
#pragma unroll
    for (int ot = 0; ot < OCT; ot++) {
      short8 bb = *(const short8*)(sB + (ot * 16 + nrow) * BP + kk * 32 + quad * 8);
      acc[ot] = __builtin_amdgcn_mfma_f32_16x16x32_bf16(a, bb, acc[ot], 0, 0, 0);
    }
  }
  int gm0 = p0 + mbase + quad * 4;
#pragma unroll
  for (int ot = 0; ot < OCT; ot++) {
    int oc = ot * 16 + nrow;
    float sc = g[oc] * rsqrtf(vr[oc] + EPS);
    float sh = bta[oc] - mn[oc] * sc;
    float v0 = acc[ot][0] * sc + sh, v1 = acc[ot][1] * sc + sh;
    float v2 = acc[ot][2] * sc + sh, v3 = acc[ot][3] * sc + sh;
    v0 = v0 >= 0.f ? v0 : 0.01f * v0;
    v1 = v1 >= 0.f ? v1 : 0.01f * v1;
    v2 = v2 >= 0.f ? v2 : 0.01f * v2;
    v3 = v3 >= 0.f ? v3 : 0.01f * v3;
    float pA = fmaxf(v0, v1), pB = fmaxf(v2, v3);
    int t0 = gm0 >> 1, t1 = t0 + 1;
    if (t0 < LOUT) out[((size_t)b * LOUT + t0) * OC + oc] = __float2bfloat16(pA);
    if (t1 < LOUT) out[((size_t)b * LOUT + t1) * OC + oc] = __float2bfloat16(pB);
  }
}

// ---------------- MFMA conv3 + bn + leaky + pool + LayerNorm fused -> xn bf16 [b][t][128], elast ----------------
__global__ __launch_bounds__(512) void kConv3LN(const __hip_bfloat16* __restrict__ in,
    const __hip_bfloat16* __restrict__ Bw, const float* __restrict__ g,
    const float* __restrict__ bta, const float* __restrict__ mn,
    const float* __restrict__ vr, const float* __restrict__ lnw,
    __hip_bfloat16* __restrict__ xn, float* __restrict__ elast) {
  constexpr int IC = 64, OC = 128, LIN = 1022, AP = 72, BP = 200, KSTEPS = 6, OCT = 8;
  __shared__ short sA[130 * AP];
  __shared__ short sB[OC * BP];
  int tid = threadIdx.x;
  int b = blockIdx.z;
  int p0 = blockIdx.x * 128;
  {
    const unsigned int* src = (const unsigned int*)Bw;
    unsigned int* dst = (unsigned int*)sB;
    for (int i = tid; i < OC * BP / 2; i += 512) dst[i] = src[i];
  }
  {
    int q = tid % 8;
    for (int r = tid / 8; r < 130; r += 64) {
      int gp = p0 + r;
      uint4 val = {0u, 0u, 0u, 0u};
      if (gp < LIN) val = *(const uint4*)((const short*)in + ((size_t)b * LIN + gp) * IC + q * 8);
      *(uint4*)(sA + r * AP + q * 8) = val;
    }
  }
  __syncthreads();
  int lane = tid & 63, w = tid >> 6;
  int nrow = lane & 15, quad = lane >> 4;
  f32x4 acc[OCT];
#pragma unroll
  for (int i = 0; i < OCT; i++) acc[i] = (f32x4){0.f, 0.f, 0.f, 0.f};
  int mbase = w * 16;
#pragma unroll
  for (int kk = 0; kk < KSTEPS; kk++) {
    int k = kk >> 1;
    int ci0 = (kk & 1) * 32;
    short8 a = *(const short8*)(sA + (mbase + nrow + k) * AP + ci0 + quad * 8);
#pragma unroll
    for (int ot = 0; ot < OCT; ot++) {
      short8 bb = *(const short8*)(sB + (ot * 16 + nrow) * BP + kk * 32 + quad * 8);
      acc[ot] = __builtin_amdgcn_mfma_f32_16x16x32_bf16(a, bb, acc[ot], 0, 0, 0);
    }
  }
  // bn + leaky + pool, keep both pooled rows per lane
  float pA[OCT], pB[OCT];
  float sA1 = 0.f, sA2 = 0.f, sB1 = 0.f, sB2 = 0.f;
#pragma unroll
  for (int ot = 0; ot < OCT; ot++) {
    int oc = ot * 16 + nrow;
    float sc = g[oc] * rsqrtf(vr[oc] + EPS);
    float sh = bta[oc] - mn[oc] * sc;
    float v0 = acc[ot][0] * sc + sh, v1 = acc[ot][1] * sc + sh;
    float v2 = acc[ot][2] * sc + sh, v3 = acc[ot][3] * sc + sh;
    v0 = v0 >= 0.f ? v0 : 0.01f * v0;
    v1 = v1 >= 0.f ? v1 : 0.01f * v1;
    v2 = v2 >= 0.f ? v2 : 0.01f * v2;
    v3 = v3 >= 0.f ? v3 : 0.01f * v3;
    float a = fmaxf(v0, v1), bb2 = fmaxf(v2, v3);
    pA[ot] = a; pB[ot] = bb2;
    sA1 += a; sA2 += a * a; sB1 += bb2; sB2 += bb2 * bb2;
  }
  // LN stats across the 16-lane (nrow) group: 8 in-reg + 16-lane reduce = 128 channels
#pragma unroll
  for (int m = 1; m <= 8; m <<= 1) {
    sA1 += __shfl_xor(sA1, m); sA2 += __shfl_xor(sA2, m);
    sB1 += __shfl_xor(sB1, m); sB2 += __shfl_xor(sB2, m);
  }
  float muA = sA1 * (1.f / 128.f);
  float rsA = rsqrtf(sA2 * (1.f / 128.f) - muA * muA + EPS);
  float muB = sB1 * (1.f / 128.f);
  float rsB = rsqrtf(sB2 * (1.f / 128.f) - muB * muB + EPS);
  int t0 = (p0 + mbase + quad * 4) >> 1, t1 = t0 + 1;
#pragma unroll
  for (int ot = 0; ot < OCT; ot++) {
    int oc = ot * 16 + nrow;
    float lw = lnw[oc];
    if (t0 < 510) xn[((size_t)b * 510 + t0) * OC + oc] = __float2bfloat16((pA[ot] - muA) * rsA * lw);
    if (t1 < 510) xn[((size_t)b * 510 + t1) * OC + oc] = __float2bfloat16((pB[ot] - muB) * rsB * lw);
    if (t1 == 509) elast[b * 128 + oc] = pB[ot];
  }
}

// ---------------- Fused dwconv+SiLU + gate projections via MFMA ----------------
// block = one (b,h). gx[s][bh][2l+slot] bf16 (same layout kRec expects).
__global__ __launch_bounds__(256) void kGxM(const __hip_bfloat16* __restrict__ xn,
    const float* __restrict__ cw, const float* __restrict__ cb,
    const float* __restrict__ wi, const float* __restrict__ wf,
    const float* __restrict__ wz, const float* __restrict__ wo,
    const float* __restrict__ rb, __hip_bfloat16* __restrict__ gx) {
  __shared__ __align__(16) char smem[29200];
  float* xnf = (float*)smem;              // [66][33] fp32          (0..8712)
  short* aX  = (short*)(smem + 8720);     // [64][40] bf16 xcv
  short* aN  = (short*)(smem + 13840);    // [64][40] bf16 xn
  short* ct  = (short*)smem;              // [64][132] C-transpose (aliases above)
  short* sW  = (short*)(smem + 18960);    // [2][64][40] weights
  int bh = blockIdx.x, b = bh >> 2, h = bh & 3;
  int tid = threadIdx.x, lane = tid & 63, w = tid >> 6;
  int nrow = lane & 15, quad = lane >> 4;
  // stage weights (bf16) : sW[slot][n][d]
  for (int idx = tid; idx < 4096; idx += 256) {
    int slot = idx >> 11, n = (idx >> 5) & 63, d = idx & 31;
    const float* wp = slot ? ((n >= 32) ? wo : wz) : ((n >= 32) ? wf : wi);
    *(__hip_bfloat16*)(sW + slot * 2560 + n * 40 + d) =
        __float2bfloat16(wp[h * 1024 + d * 32 + (n & 31)]);
  }
  int dd = tid & 31;
  float cw0 = cw[(h * 32 + dd) * 3], cw1 = cw[(h * 32 + dd) * 3 + 1],
        cw2 = cw[(h * 32 + dd) * 3 + 2], cbv = cb[h * 32 + dd];
  float bias0[4], bias1[4];
#pragma unroll
  for (int nt = 0; nt < 4; nt++) {
    int n = nt * 16 + nrow;
    bias0[nt] = rb[(n >> 5) * 128 + h * 32 + (n & 31)];
    bias1[nt] = rb[(2 + (n >> 5)) * 128 + h * 32 + (n & 31)];
  }
  __syncthreads();
  short8 bw0[4], bw1[4];
#pragma unroll
  for (int nt = 0; nt < 4; nt++) {
    bw0[nt] = *(const short8*)(sW + (nt * 16 + nrow) * 40 + quad * 8);
    bw1[nt] = *(const short8*)(sW + 2560 + (nt * 16 + nrow) * 40 + quad * 8);
  }
  const unsigned short* xb = (const unsigned short*)xn + ((size_t)b * 510) * 128 + h * 32;
  for (int s0 = 0; s0 < 510; s0 += 64) {
    __syncthreads();  // prev tile's ct fully copied
    {
      int d2 = tid & 15;
      for (int r = tid >> 4; r < 66; r += 16) {
        int s = s0 - 2 + r;
        unsigned int v = 0;
        if (s >= 0 && s < 510) v = *(const unsigned int*)(xb + (size_t)s * 128 + d2 * 2);
        xnf[r * 33 + d2 * 2]     = __uint_as_float(v << 16);
        xnf[r * 33 + d2 * 2 + 1] = __uint_as_float(v & 0xFFFF0000u);
      }
    }
    __syncthreads();
    for (int m = tid >> 5; m < 64; m += 8) {
      float x0 = xnf[m * 33 + dd], x1 = xnf[(m + 1) * 33 + dd], x2 = xnf[(m + 2) * 33 + dd];
      float a = cbv + cw0 * x0 + cw1 * x1 + cw2 * x2;
      a = a * __builtin_amdgcn_rcpf(1.f + __expf(-a));
      *(__hip_bfloat16*)(aX + m * 40 + dd) = __float2bfloat16(a);
      *(__hip_bfloat16*)(aN + m * 40 + dd) = __float2bfloat16(x2);
    }
    __syncthreads();
    f32x4 z = (f32x4){0.f, 0.f, 0.f, 0.f};
    short8 ax = *(const short8*)(aX + (w * 16 + nrow) * 40 + quad * 8);
    short8 an = *(const short8*)(aN + (w * 16 + nrow) * 40 + quad * 8);
    f32x4 acc0[4], acc1[4];
#pragma unroll
    for (int nt = 0; nt < 4; nt++) {
      acc0[nt] = __builtin_amdgcn_mfma_f32_16x16x32_bf16(ax, bw0[nt], z, 0, 0, 0);
      acc1[nt] = __builtin_amdgcn_mfma_f32_16x16x32_bf16(an, bw1[nt], z, 0, 0, 0);
    }
    __syncthreads();  // A-frag reads drained before ct overwrite
#pragma unroll
    for (int nt = 0; nt < 4; nt++) {
#pragma unroll
      for (int r = 0; r < 4; r++) {
        int row = w * 16 + quad * 4 + r;
        ct[row * 132 + 2 * (nt * 16 + nrow)]     = bf16s(acc0[nt][r] + bias0[nt]);
        ct[row * 132 + 2 * (nt * 16 + nrow) + 1] = bf16s(acc1[nt][r] + bias1[nt]);
      }
    }
    __syncthreads();
    {
      int u = tid & 63;
      for (int m = tid >> 6; m < 64; m += 4) {
        int s = s0 + m;
        if (s < 510)
          *((unsigned int*)gx + ((size_t)s * 1024 + bh) * 64 + u) =
              *(const unsigned int*)(ct + m * 132 + 2 * u);
      }
    }
  }
}

// ---------------- Lean sLSTM recurrence: readlane y-broadcast ----------------
__global__ __launch_bounds__(64) void kRec(const unsigned int* __restrict__ gx,
    const float* __restrict__ rk, float* __restrict__ yf) {
  int bh = blockIdx.x; int h = bh & 3;
  int l = threadIdx.x; int half = l >> 5; int e = l & 31;
  float R1[32], R2[32];
  int g1 = half, g2 = 2 + half;
  const float* r1p = rk + h * 4096 + g1 * 32 + e;
  const float* r2p = rk + h * 4096 + g2 * 32 + e;
#pragma unroll
  for (int d = 0; d < 32; d++) { R1[d] = r1p[d * 128]; R2[d] = r2p[d * 128]; }
  const unsigned int* gp = gx + (size_t)bh * 64 + l;
  unsigned int p0 = gp[0], p1 = gp[65536], p2 = gp[131072], p3 = gp[196608];
  float y = 0.f, cst = 0.f, nst = 0.f, mst = 0.f;
  for (int s = 0; s < 510; s++) {
    unsigned int pc = p0; p0 = p1; p1 = p2; p2 = p3;
    if (s + 4 < 510) p3 = gp[(size_t)(s + 4) * 65536];
    float a1 = __uint_as_float(pc << 16);
    float a2 = __uint_as_float(pc & 0xFFFF0000u);
    float s10 = 0.f, s11 = 0.f, s12 = 0.f, s13 = 0.f;
    float s20 = 0.f, s21 = 0.f, s22 = 0.f, s23 = 0.f;
    unsigned int yb = __float_as_uint(y);
#pragma unroll
    for (int d = 0; d < 32; d += 4) {
      float y0 = __uint_as_float(__builtin_amdgcn_readlane(yb, d));
      float y1 = __uint_as_float(__builtin_amdgcn_readlane(yb, d + 1));
      float y2 = __uint_as_float(__builtin_amdgcn_readlane(yb, d + 2));
      float y3 = __uint_as_float(__builtin_amdgcn_readlane(yb, d + 3));
      s10 = fmaf(y0, R1[d], s10);     s20 = fmaf(y0, R2[d], s20);
      s11 = fmaf(y1, R1[d + 1], s11); s21 = fmaf(y1, R2[d + 1], s21);
      s12 = fmaf(y2, R1[d + 2], s12); s22 = fmaf(y2, R2[d + 2], s22);
      s13 = fmaf(y3, R1[d + 3], s13); s23 = fmaf(y3, R2[d + 3], s23);
    }
    a1 += (s10 + s11) + (s12 + s13);
    a2 += (s20 + s21) + (s22 + s23);
    float en = __expf(-fabsf(a1));
    float ls = fminf(a1, 0.f) - __logf(1.f + en);             // log-sigmoid(a1)
    float sg = __builtin_amdgcn_rcpf(1.f + __expf(-a2));      // sigmoid(a2)
    float tz = 1.f - 2.f * __builtin_amdgcn_rcpf(__expf(2.f * a2) + 1.f);  // tanh(a2)
    float lsf = __shfl_xor(ls, 32);
    float so  = __shfl_xor(sg, 32);
    float lf = mst + lsf;
    float mnew = fmaxf(a1, lf);
    float ig = __expf(a1 - mnew);
    float fg = __expf(lf - mnew);
    cst = fg * cst + ig * tz;
    nst = fg * nst + ig;
    mst = mnew;
    y = so * cst * __builtin_amdgcn_rcpf(nst);
  }
  if (half == 0) yf[(bh >> 2) * 128 + h * 32 + e] = y;
}

// ---------------- Tail for the last timestep only ----------------
__global__ __launch_bounds__(128) void kHead(const float* __restrict__ yf,
    const float* __restrict__ elast, const float* __restrict__ gnw,
    const float* __restrict__ ln2w, const float* __restrict__ upw,
    const float* __restrict__ dnw, const float* __restrict__ lnpw,
    const float* __restrict__ fcw, const float* __restrict__ fcb,
    float* __restrict__ outp) {
  int c = threadIdx.x; int b = blockIdx.x;
  __shared__ float sred[4];
  __shared__ float sx[128];
  __shared__ float sup[384];
  __shared__ float shh[192];
  float yv = yf[b * 128 + c];
  float s1 = yv, s2 = yv * yv;
#pragma unroll
  for (int m = 1; m <= 16; m <<= 1) { s1 += __shfl_xor(s1, m); s2 += __shfl_xor(s2, m); }
  float mu = s1 * (1.f / 32.f);
  float var = s2 * (1.f / 32.f) - mu * mu;
  float yn = (yv - mu) * rsqrtf(var + EPS) * gnw[c];
  float el = elast[b * 128 + c] + yn;
  auto ln128 = [&](float v, const float* w) -> float {
    float a = v, a2 = v * v;
#pragma unroll
    for (int m = 1; m <= 32; m <<= 1) { a += __shfl_xor(a, m); a2 += __shfl_xor(a2, m); }
    int wv = c >> 6;
    if ((c & 63) == 0) { sred[wv * 2] = a; sred[wv * 2 + 1] = a2; }
    __syncthreads();
    float t1 = sred[0] + sred[2], t2 = sred[1] + sred[3];
    __syncthreads();
    float mm = t1 * (1.f / 128.f);
    float vv = t2 * (1.f / 128.f) - mm * mm;
    return (v - mm) * rsqrtf(vv + EPS) * w[c];
  };
  float xn2 = ln128(el, ln2w);
  sx[c] = xn2;
  __syncthreads();
#pragma unroll
  for (int jj = 0; jj < 3; jj++) {
    int j = c + jj * 128;
    float acc = 0.f;
    for (int k = 0; k < 128; k++) acc += sx[k] * upw[k * 384 + j];
    sup[j] = acc;
  }
  __syncthreads();
  {
    float u = sup[c]; float mg = sup[192 + c];
    shh[c] = 0.5f * u * (1.f + erff(u * 0.70710678118654752f)) * mg;
    if (c < 64) {
      float u2 = sup[128 + c]; float m2 = sup[320 + c];
      shh[128 + c] = 0.5f * u2 * (1.f + erff(u2 * 0.70710678118654752f)) * m2;
    }
  }
  __syncthreads();
  float acc = 0.f;
  for (int f = 0; f < 192; f++) acc += shh[f] * dnw[f * 128 + c];
  float e2 = el + acc;
  float e3 = ln128(e2, lnpw);
  sx[c] = e3;
  __syncthreads();
  if (c < 5) {
    float a = fcb[c];
    for (int k = 0; k < 128; k++) a += sx[k] * fcw[k * 5 + c];
    outp[b * 5 + c] = a;
  }
}

extern "C" void kernel_launch(void* const* d_in, const int* in_sizes, int n_in,
                              void* d_out, int out_size, void* d_ws, size_t ws_size,
                              hipStream_t stream) {
  const float* x    = (const float*)d_in[0];
  const float* w1a  = (const float*)d_in[1];
  const float* w1b  = (const float*)d_in[2];
  const float* bn1g = (const float*)d_in[3];
  const float* bn1b = (const float*)d_in[4];
  const float* bn1m = (const float*)d_in[5];
  const float* bn1v = (const float*)d_in[6];
  const float* w2   = (const float*)d_in[7];
  const float* bn2g = (const float*)d_in[8];
  const float* bn2b = (const float*)d_in[9];
  const float* bn2m = (const float*)d_in[10];
  const float* bn2v = (const float*)d_in[11];
  const float* w3   = (const float*)d_in[12];
  const float* bn3g = (const float*)d_in[13];
  const float* bn3b = (const float*)d_in[14];
  const float* bn3m = (const float*)d_in[15];
  const float* bn3v = (const float*)d_in[16];
  const float* ln1w = (const float*)d_in[17];
  const float* cw   = (const float*)d_in[18];
  const float* cb   = (const float*)d_in[19];
  const float* wi   = (const float*)d_in[20];
  const float* wf   = (const float*)d_in[21];
  const float* wz   = (const float*)d_in[22];
  const float* wo   = (const float*)d_in[23];
  const float* rk   = (const float*)d_in[24];
  const float* rb   = (const float*)d_in[25];
  const float* gnw  = (const float*)d_in[26];
  const float* ln2w = (const float*)d_in[27];
  const float* upw  = (const float*)d_in[28];
  const float* dnw  = (const float*)d_in[29];
  const float* lnpw = (const float*)d_in[30];
  const float* fcw  = (const float*)d_in[31];
  const float* fcb  = (const float*)d_in[32];
  float* outp = (float*)d_out;

  char* ws = (char*)d_ws;
  __hip_bfloat16* out1 = (__hip_bfloat16*)ws;                        // [256][2047][32] 33.5MB
  __hip_bfloat16* xnb  = (__hip_bfloat16*)ws;                        // [256][510][128] 33.4MB (out1 dead)
  __hip_bfloat16* out2 = (__hip_bfloat16*)(ws + ((size_t)64 << 20)); // [256][1022][64] 33.5MB
  __hip_bfloat16* gxb  = (__hip_bfloat16*)(ws + ((size_t)128 << 20)); // 133.7MB
  float* elast = (float*)(ws + ((size_t)258 << 20));
  float* yfin  = (float*)(ws + ((size_t)259 << 20));
  __hip_bfloat16* wtg2b = (__hip_bfloat16*)(ws + ((size_t)260 << 20));
  __hip_bfloat16* wtg3b = (__hip_bfloat16*)(ws + ((size_t)260 << 20) + (1 << 20));

  kWTB2<<<dim3(126), 256, 0, stream>>>(w2, w3, wtg2b, wtg3b);
  kA<<<dim3(256, 1, 256), 256, 0, stream>>>(x, w1a, w1b, bn1g, bn1b, bn1m, bn1v, out1);
  kConvM<32, 64, 2047, 1022, 40, 104><<<dim3(16, 1, 256), 512, 0, stream>>>(
      out1, wtg2b, bn2g, bn2b, bn2m, bn2v, out2);
  kConv3LN<<<dim3(8, 1, 256), 512, 0, stream>>>(
      out2, wtg3b, bn3g, bn3b, bn3m, bn3v, ln1w, xnb, elast);
  kGxM<<<dim3(1024), 256, 0, stream>>>(xnb, cw, cb, wi, wf, wz, wo, rb, gxb);
  kRec<<<dim3(1024), 64, 0, stream>>>((const unsigned int*)gxb, rk, yfin);
  kHead<<<dim3(256), 128, 0, stream>>>(yfin, elast, gnw, ln2w, upw, dnw, lnpw, fcw, fcb, outp);
}

// Round 8
// 608.844 us; speedup vs baseline: 2.9108x; 1.1001x over previous
//
#include <hip/hip_runtime.h>
#include <hip/hip_bf16.h>
#include <math.h>

#define EPS 1e-5f

typedef __attribute__((ext_vector_type(8))) _Float16 half8;
typedef __attribute__((ext_vector_type(4))) float f32x4;

static __device__ __forceinline__ unsigned short f16u(float x) {
  _Float16 h = (_Float16)x;  // RTN
  return *(unsigned short*)&h;
}
static __device__ __forceinline__ float uf16(unsigned short u) {
  _Float16 h = *(_Float16*)&u;
  return (float)h;
}

// ---------------- Combined weight transform for conv2+conv3: -> B^T f16 padded ----------------
__global__ __launch_bounds__(256) void kWTB2(const float* __restrict__ w2,
    const float* __restrict__ w3, unsigned short* __restrict__ o2,
    unsigned short* __restrict__ o3) {
  int idx = blockIdx.x * 256 + threadIdx.x;
  if (idx < 64 * 104) {
    int oc = idx / 104, kp = idx % 104;
    float v = 0.f;
    if (kp < 96) { int k = kp >> 5, ci = kp & 31; v = w2[oc * 96 + ci * 3 + k]; }
    o2[idx] = f16u(v);
  } else {
    int j = idx - 64 * 104;
    if (j < 128 * 200) {
      int oc = j / 200, kp = j % 200;
      float v = 0.f;
      if (kp < 192) { int k = kp >> 6, ci = kp & 63; v = w3[oc * 192 + ci * 3 + k]; }
      o3[j] = f16u(v);
    }
  }
}

// ---------------- Fused conv1(+bn1+leaky+pool) in-register + conv2 MFMA (+bn2+leaky+pool) ----------------
// x [256][4096][2] -> out2 f16 [256][1022][64]
__global__ __launch_bounds__(512) void kConv12(const float* __restrict__ x,
    const float* __restrict__ w1a, const float* __restrict__ w1b,
    const float* __restrict__ g1, const float* __restrict__ b1,
    const float* __restrict__ m1, const float* __restrict__ v1,
    const unsigned short* __restrict__ Bw, const float* __restrict__ g2,
    const float* __restrict__ b2, const float* __restrict__ m2,
    const float* __restrict__ v2, unsigned short* __restrict__ out2) {
  __shared__ _Float16 sA[130 * 40];
  __shared__ _Float16 sB[64 * 104];
  int tid = threadIdx.x;
  int b = blockIdx.z;
  int p0 = blockIdx.x * 128;  // conv2 pre-pool row base (= conv1-pooled row index)
  // stage conv2 weights
  {
    const unsigned int* src = (const unsigned int*)Bw;
    unsigned int* dst = (unsigned int*)sB;
    for (int i = tid; i < 64 * 104 / 2; i += 512) dst[i] = src[i];
  }
  // compute conv1 + bn1 + leaky + pool directly into sA (f16)
  {
    int c = tid & 31, rg = tid >> 5;  // rg in [0,16)
    float sc1 = g1[c] * rsqrtf(v1[c] + EPS);
    float sh1 = b1[c] - m1[c] * sc1;
    float wk0[4], wk1[4];
    if (c < 16) {
#pragma unroll
      for (int k = 0; k < 4; k++) { wk0[k] = w1a[c * 8 + k]; wk1[k] = w1a[c * 8 + 4 + k]; }
    } else {
      int cc = c - 16;
#pragma unroll
      for (int k = 0; k < 2; k++) { wk0[k] = w1b[cc * 4 + k]; wk1[k] = w1b[cc * 4 + 2 + k]; }
      wk0[2] = wk0[3] = wk1[2] = wk1[3] = 0.f;
    }
    const float2* xp = (const float2*)(x + (size_t)b * 8192);
    for (int r = rg; r < 130; r += 16) {
      int rr = p0 + r;
      _Float16 outv = (_Float16)0.f;
      if (rr < 2047) {
        float xv0[5], xv1[5];
#pragma unroll
        for (int j = 0; j < 5; j++) {
          int l = 2 * rr - 1 + j;
          if (l >= 0 && l < 4096) { float2 v = xp[l]; xv0[j] = v.x; xv1[j] = v.y; }
          else { xv0[j] = 0.f; xv1[j] = 0.f; }
        }
        float a0 = 0.f, a1 = 0.f;
        if (c < 16) {
#pragma unroll
          for (int k = 0; k < 4; k++) {
            a0 += xv0[k] * wk0[k] + xv1[k] * wk1[k];
            a1 += xv0[k + 1] * wk0[k] + xv1[k + 1] * wk1[k];
          }
        } else {
#pragma unroll
          for (int k = 0; k < 2; k++) {
            a0 += xv0[k + 1] * wk0[k] + xv1[k + 1] * wk1[k];
            a1 += xv0[k + 2] * wk0[k] + xv1[k + 2] * wk1[k];
          }
        }
        a0 = a0 * sc1 + sh1; a1 = a1 * sc1 + sh1;
        a0 = a0 >= 0.f ? a0 : 0.01f * a0;
        a1 = a1 >= 0.f ? a1 : 0.01f * a1;
        outv = (_Float16)fmaxf(a0, a1);
      }
      sA[r * 40 + c] = outv;
    }
  }
  __syncthreads();
  // conv2 MFMA: M=128 pre-pool rows, N=64, K=96
  int lane = tid & 63, w = tid >> 6;
  int nrow = lane & 15, quad = lane >> 4;
  f32x4 acc[4];
#pragma unroll
  for (int i = 0; i < 4; i++) acc[i] = (f32x4){0.f, 0.f, 0.f, 0.f};
  int mbase = w * 16;
#pragma unroll
  for (int kk = 0; kk < 3; kk++) {
    half8 a = *(const half8*)(sA + (mbase + nrow + kk) * 40 + quad * 8);
#pragma unroll
    for (int ot = 0; ot < 4; ot++) {
      half8 bb = *(const half8*)(sB + (ot * 16 + nrow) * 104 + kk * 32 + quad * 8);
      acc[ot] = __builtin_amdgcn_mfma_f32_16x16x32_f16(a, bb, acc[ot], 0, 0, 0);
    }
  }
  int gm0 = p0 + mbase + quad * 4;
#pragma unroll
  for (int ot = 0; ot < 4; ot++) {
    int oc = ot * 16 + nrow;
    float sc = g2[oc] * rsqrtf(v2[oc] + EPS);
    float sh = b2[oc] - m2[oc] * sc;
    float v0 = acc[ot][0] * sc + sh, vv1 = acc[ot][1] * sc + sh;
    float v2e = acc[ot][2] * sc + sh, v3 = acc[ot][3] * sc + sh;
    v0 = v0 >= 0.f ? v0 : 0.01f * v0;
    vv1 = vv1 >= 0.f ? vv1 : 0.01f * vv1;
    v2e = v2e >= 0.f ? v2e : 0.01f * v2e;
    v3 = v3 >= 0.f ? v3 : 0.01f * v3;
    float pA = fmaxf(v0, vv1), pB = fmaxf(v2e, v3);
    int t0 = gm0 >> 1, t1 = t0 + 1;
    if (t0 < 1022) out2[((size_t)b * 1022 + t0) * 64 + oc] = f16u(pA);
    if (t1 < 1022) out2[((size_t)b * 1022 + t1) * 64 + oc] = f16u(pB);
  }
}

// ---------------- MFMA conv3 + bn + leaky + pool + LayerNorm fused -> xn f16 [b][t][128], elast ----------------
__global__ __launch_bounds__(512) void kConv3LN(const unsigned short* __restrict__ in,
    const unsigned short* __restrict__ Bw, const float* __restrict__ g,
    const float* __restrict__ bta, const float* __restrict__ mn,
    const float* __restrict__ vr, const float* __restrict__ lnw,
    unsigned short* __restrict__ xn, float* __restrict__ elast) {
  constexpr int IC = 64, OC = 128, LIN = 1022, AP = 72, BP = 200, KSTEPS = 6, OCT = 8;
  __shared__ _Float16 sA[130 * AP];
  __shared__ _Float16 sB[OC * BP];
  int tid = threadIdx.x;
  int b = blockIdx.z;
  int p0 = blockIdx.x * 128;
  {
    const unsigned int* src = (const unsigned int*)Bw;
    unsigned int* dst = (unsigned int*)sB;
    for (int i = tid; i < OC * BP / 2; i += 512) dst[i] = src[i];
  }
  {
    int q = tid % 8;
    for (int r = tid / 8; r < 130; r += 64) {
      int gp = p0 + r;
      uint4 val = {0u, 0u, 0u, 0u};
      if (gp < LIN) val = *(const uint4*)(in + ((size_t)b * LIN + gp) * IC + q * 8);
      *(uint4*)(sA + r * AP + q * 8) = val;
    }
  }
  __syncthreads();
  int lane = tid & 63, w = tid >> 6;
  int nrow = lane & 15, quad = lane >> 4;
  f32x4 acc[OCT];
#pragma unroll
  for (int i = 0; i < OCT; i++) acc[i] = (f32x4){0.f, 0.f, 0.f, 0.f};
  int mbase = w * 16;
#pragma unroll
  for (int kk = 0; kk < KSTEPS; kk++) {
    int k = kk >> 1;
    int ci0 = (kk & 1) * 32;
    half8 a = *(const half8*)(sA + (mbase + nrow + k) * AP + ci0 + quad * 8);
#pragma unroll
    for (int ot = 0; ot < OCT; ot++) {
      half8 bb = *(const half8*)(sB + (ot * 16 + nrow) * BP + kk * 32 + quad * 8);
      acc[ot] = __builtin_amdgcn_mfma_f32_16x16x32_f16(a, bb, acc[ot], 0, 0, 0);
    }
  }
  // bn + leaky + pool, keep both pooled rows per lane
  float pA[OCT], pB[OCT];
  float sA1 = 0.f, sA2 = 0.f, sB1 = 0.f, sB2 = 0.f;
#pragma unroll
  for (int ot = 0; ot < OCT; ot++) {
    int oc = ot * 16 + nrow;
    float sc = g[oc] * rsqrtf(vr[oc] + EPS);
    float sh = bta[oc] - mn[oc] * sc;
    float v0 = acc[ot][0] * sc + sh, v1 = acc[ot][1] * sc + sh;
    float v2 = acc[ot][2] * sc + sh, v3 = acc[ot][3] * sc + sh;
    v0 = v0 >= 0.f ? v0 : 0.01f * v0;
    v1 = v1 >= 0.f ? v1 : 0.01f * v1;
    v2 = v2 >= 0.f ? v2 : 0.01f * v2;
    v3 = v3 >= 0.f ? v3 : 0.01f * v3;
    float a = fmaxf(v0, v1), bb2 = fmaxf(v2, v3);
    pA[ot] = a; pB[ot] = bb2;
    sA1 += a; sA2 += a * a; sB1 += bb2; sB2 += bb2 * bb2;
  }
#pragma unroll
  for (int m = 1; m <= 8; m <<= 1) {
    sA1 += __shfl_xor(sA1, m); sA2 += __shfl_xor(sA2, m);
    sB1 += __shfl_xor(sB1, m); sB2 += __shfl_xor(sB2, m);
  }
  float muA = sA1 * (1.f / 128.f);
  float rsA = rsqrtf(sA2 * (1.f / 128.f) - muA * muA + EPS);
  float muB = sB1 * (1.f / 128.f);
  float rsB = rsqrtf(sB2 * (1.f / 128.f) - muB * muB + EPS);
  int t0 = (p0 + mbase + quad * 4) >> 1, t1 = t0 + 1;
#pragma unroll
  for (int ot = 0; ot < OCT; ot++) {
    int oc = ot * 16 + nrow;
    float lw = lnw[oc];
    if (t0 < 510) xn[((size_t)b * 510 + t0) * OC + oc] = f16u((pA[ot] - muA) * rsA * lw);
    if (t1 < 510) xn[((size_t)b * 510 + t1) * OC + oc] = f16u((pB[ot] - muB) * rsB * lw);
    if (t1 == 509) elast[b * 128 + oc] = pB[ot];
  }
}

// ---------------- Fused dwconv+SiLU + gate projections via MFMA (f16) ----------------
// block = one (b,h). gx[s][bh][2l+slot] f16 (layout kRec expects).
__global__ __launch_bounds__(256) void kGxM(const unsigned short* __restrict__ xn,
    const float* __restrict__ cw, const float* __restrict__ cb,
    const float* __restrict__ wi, const float* __restrict__ wf,
    const float* __restrict__ wz, const float* __restrict__ wo,
    const float* __restrict__ rb, unsigned int* __restrict__ gx) {
  __shared__ __align__(16) char smem[29200];
  float* xnf = (float*)smem;                  // [66][33] fp32        (0..8712)
  _Float16* aX = (_Float16*)(smem + 8720);    // [64][40] f16 xcv
  _Float16* aN = (_Float16*)(smem + 13840);   // [64][40] f16 xn
  unsigned short* ct = (unsigned short*)smem; // [64][132] C-transpose (aliases above)
  _Float16* sW = (_Float16*)(smem + 18960);   // [2][64][40] weights
  int bh = blockIdx.x, b = bh >> 2, h = bh & 3;
  int tid = threadIdx.x, lane = tid & 63, w = tid >> 6;
  int nrow = lane & 15, quad = lane >> 4;
  for (int idx = tid; idx < 4096; idx += 256) {
    int slot = idx >> 11, n = (idx >> 5) & 63, d = idx & 31;
    const float* wp = slot ? ((n >= 32) ? wo : wz) : ((n >= 32) ? wf : wi);
    sW[slot * 2560 + n * 40 + d] = (_Float16)wp[h * 1024 + d * 32 + (n & 31)];
  }
  int dd = tid & 31;
  float cw0 = cw[(h * 32 + dd) * 3], cw1 = cw[(h * 32 + dd) * 3 + 1],
        cw2 = cw[(h * 32 + dd) * 3 + 2], cbv = cb[h * 32 + dd];
  float bias0[4], bias1[4];
#pragma unroll
  for (int nt = 0; nt < 4; nt++) {
    int n = nt * 16 + nrow;
    bias0[nt] = rb[(n >> 5) * 128 + h * 32 + (n & 31)];
    bias1[nt] = rb[(2 + (n >> 5)) * 128 + h * 32 + (n & 31)];
  }
  __syncthreads();
  half8 bw0[4], bw1[4];
#pragma unroll
  for (int nt = 0; nt < 4; nt++) {
    bw0[nt] = *(const half8*)(sW + (nt * 16 + nrow) * 40 + quad * 8);
    bw1[nt] = *(const half8*)(sW + 2560 + (nt * 16 + nrow) * 40 + quad * 8);
  }
  const unsigned short* xb = xn + ((size_t)b * 510) * 128 + h * 32;
  for (int s0 = 0; s0 < 510; s0 += 64) {
    __syncthreads();  // prev tile's ct fully copied
    {
      int d2 = tid & 15;
      for (int r = tid >> 4; r < 66; r += 16) {
        int s = s0 - 2 + r;
        unsigned int v = 0;
        if (s >= 0 && s < 510) v = *(const unsigned int*)(xb + (size_t)s * 128 + d2 * 2);
        xnf[r * 33 + d2 * 2]     = uf16(v & 0xFFFFu);
        xnf[r * 33 + d2 * 2 + 1] = uf16(v >> 16);
      }
    }
    __syncthreads();
    for (int m = tid >> 5; m < 64; m += 8) {
      float x0 = xnf[m * 33 + dd], x1 = xnf[(m + 1) * 33 + dd], x2 = xnf[(m + 2) * 33 + dd];
      float a = cbv + cw0 * x0 + cw1 * x1 + cw2 * x2;
      a = a * __builtin_amdgcn_rcpf(1.f + __expf(-a));
      aX[m * 40 + dd] = (_Float16)a;
      aN[m * 40 + dd] = (_Float16)x2;
    }
    __syncthreads();
    f32x4 z = (f32x4){0.f, 0.f, 0.f, 0.f};
    half8 ax = *(const half8*)(aX + (w * 16 + nrow) * 40 + quad * 8);
    half8 an = *(const half8*)(aN + (w * 16 + nrow) * 40 + quad * 8);
    f32x4 acc0[4], acc1[4];
#pragma unroll
    for (int nt = 0; nt < 4; nt++) {
      acc0[nt] = __builtin_amdgcn_mfma_f32_16x16x32_f16(ax, bw0[nt], z, 0, 0, 0);
      acc1[nt] = __builtin_amdgcn_mfma_f32_16x16x32_f16(an, bw1[nt], z, 0, 0, 0);
    }
    __syncthreads();  // A-frag reads drained before ct overwrite
#pragma unroll
    for (int nt = 0; nt < 4; nt++) {
#pragma unroll
      for (int r = 0; r < 4; r++) {
        int row = w * 16 + quad * 4 + r;
        ct[row * 132 + 2 * (nt * 16 + nrow)]     = f16u(acc0[nt][r] + bias0[nt]);
        ct[row * 132 + 2 * (nt * 16 + nrow) + 1] = f16u(acc1[nt][r] + bias1[nt]);
      }
    }
    __syncthreads();
    {
      int u = tid & 63;
      for (int m = tid >> 6; m < 64; m += 4) {
        int s = s0 + m;
        if (s < 510)
          gx[((size_t)s * 1024 + bh) * 64 + u] = *(const unsigned int*)(ct + m * 132 + 2 * u);
      }
    }
  }
}

// ---------------- Lean sLSTM recurrence: readlane y-broadcast; f16 gx unpack ----------------
__global__ __launch_bounds__(64) void kRec(const unsigned int* __restrict__ gx,
    const float* __restrict__ rk, float* __restrict__ yf) {
  int bh = blockIdx.x; int h = bh & 3;
  int l = threadIdx.x; int half = l >> 5; int e = l & 31;
  float R1[32], R2[32];
  int g1 = half, g2 = 2 + half;
  const float* r1p = rk + h * 4096 + g1 * 32 + e;
  const float* r2p = rk + h * 4096 + g2 * 32 + e;
#pragma unroll
  for (int d = 0; d < 32; d++) { R1[d] = r1p[d * 128]; R2[d] = r2p[d * 128]; }
  const unsigned int* gp = gx + (size_t)bh * 64 + l;
  unsigned int p0 = gp[0], p1 = gp[65536], p2 = gp[131072], p3 = gp[196608];
  float y = 0.f, cst = 0.f, nst = 0.f, mst = 0.f;
  for (int s = 0; s < 510; s++) {
    unsigned int pc = p0; p0 = p1; p1 = p2; p2 = p3;
    if (s + 4 < 510) p3 = gp[(size_t)(s + 4) * 65536];
    float a1 = uf16(pc & 0xFFFFu);   // pre (i/f)
    float a2 = uf16(pc >> 16);       // pre (z/o)
    float s10 = 0.f, s11 = 0.f, s12 = 0.f, s13 = 0.f;
    float s20 = 0.f, s21 = 0.f, s22 = 0.f, s23 = 0.f;
    unsigned int yb = __float_as_uint(y);
#pragma unroll
    for (int d = 0; d < 32; d += 4) {
      float y0 = __uint_as_float(__builtin_amdgcn_readlane(yb, d));
      float y1 = __uint_as_float(__builtin_amdgcn_readlane(yb, d + 1));
      float y2 = __uint_as_float(__builtin_amdgcn_readlane(yb, d + 2));
      float y3 = __uint_as_float(__builtin_amdgcn_readlane(yb, d + 3));
      s10 = fmaf(y0, R1[d], s10);     s20 = fmaf(y0, R2[d], s20);
      s11 = fmaf(y1, R1[d + 1], s11); s21 = fmaf(y1, R2[d + 1], s21);
      s12 = fmaf(y2, R1[d + 2], s12); s22 = fmaf(y2, R2[d + 2], s22);
      s13 = fmaf(y3, R1[d + 3], s13); s23 = fmaf(y3, R2[d + 3], s23);
    }
    a1 += (s10 + s11) + (s12 + s13);
    a2 += (s20 + s21) + (s22 + s23);
    float en = __expf(-fabsf(a1));
    float ls = fminf(a1, 0.f) - __logf(1.f + en);             // log-sigmoid(a1)
    float sg = __builtin_amdgcn_rcpf(1.f + __expf(-a2));      // sigmoid(a2)
    float tz = 1.f - 2.f * __builtin_amdgcn_rcpf(__expf(2.f * a2) + 1.f);  // tanh(a2)
    float lsf = __shfl_xor(ls, 32);
    float so  = __shfl_xor(sg, 32);
    float lf = mst + lsf;
    float mnew = fmaxf(a1, lf);
    float ig = __expf(a1 - mnew);
    float fg = __expf(lf - mnew);
    cst = fg * cst + ig * tz;
    nst = fg * nst + ig;
    mst = mnew;
    y = so * cst * __builtin_amdgcn_rcpf(nst);
  }
  if (half == 0) yf[(bh >> 2) * 128 + h * 32 + e] = y;
}

// ---------------- Tail for the last timestep only ----------------
__global__ __launch_bounds__(128) void kHead(const float* __restrict__ yf,
    const float* __restrict__ elast, const float* __restrict__ gnw,
    const float* __restrict__ ln2w, const float* __restrict__ upw,
    const float* __restrict__ dnw, const float* __restrict__ lnpw,
    const float* __restrict__ fcw, const float* __restrict__ fcb,
    float* __restrict__ outp) {
  int c = threadIdx.x; int b = blockIdx.x;
  __shared__ float sred[4];
  __shared__ float sx[128];
  __shared__ float sup[384];
  __shared__ float shh[192];
  float yv = yf[b * 128 + c];
  float s1 = yv, s2 = yv * yv;
#pragma unroll
  for (int m = 1; m <= 16; m <<= 1) { s1 += __shfl_xor(s1, m); s2 += __shfl_xor(s2, m); }
  float mu = s1 * (1.f / 32.f);
  float var = s2 * (1.f / 32.f) - mu * mu;
  float yn = (yv - mu) * rsqrtf(var + EPS) * gnw[c];
  float el = elast[b * 128 + c] + yn;
  auto ln128 = [&](float v, const float* w) -> float {
    float a = v, a2 = v * v;
#pragma unroll
    for (int m = 1; m <= 32; m <<= 1) { a += __shfl_xor(a, m); a2 += __shfl_xor(a2, m); }
    int wv = c >> 6;
    if ((c & 63) == 0) { sred[wv * 2] = a; sred[wv * 2 + 1] = a2; }
    __syncthreads();
    float t1 = sred[0] + sred[2], t2 = sred[1] + sred[3];
    __syncthreads();
    float mm = t1 * (1.f / 128.f);
    float vv = t2 * (1.f / 128.f) - mm * mm;
    return (v - mm) * rsqrtf(vv + EPS) * w[c];
  };
  float xn2 = ln128(el, ln2w);
  sx[c] = xn2;
  __syncthreads();
#pragma unroll
  for (int jj = 0; jj < 3; jj++) {
    int j = c + jj * 128;
    float acc = 0.f;
    for (int k = 0; k < 128; k++) acc += sx[k] * upw[k * 384 + j];
    sup[j] = acc;
  }
  __syncthreads();
  {
    float u = sup[c]; float mg = sup[192 + c];
    shh[c] = 0.5f * u * (1.f + erff(u * 0.70710678118654752f)) * mg;
    if (c < 64) {
      float u2 = sup[128 + c]; float m2 = sup[320 + c];
      shh[128 + c] = 0.5f * u2 * (1.f + erff(u2 * 0.70710678118654752f)) * m2;
    }
  }
  __syncthreads();
  float acc = 0.f;
  for (int f = 0; f < 192; f++) acc += shh[f] * dnw[f * 128 + c];
  float e2 = el + acc;
  float e3 = ln128(e2, lnpw);
  sx[c] = e3;
  __syncthreads();
  if (c < 5) {
    float a = fcb[c];
    for (int k = 0; k < 128; k++) a += sx[k] * fcw[k * 5 + c];
    outp[b * 5 + c] = a;
  }
}

extern "C" void kernel_launch(void* const* d_in, const int* in_sizes, int n_in,
                              void* d_out, int out_size, void* d_ws, size_t ws_size,
                              hipStream_t stream) {
  const float* x    = (const float*)d_in[0];
  const float* w1a  = (const float*)d_in[1];
  const float* w1b  = (const float*)d_in[2];
  const float* bn1g = (const float*)d_in[3];
  const float* bn1b = (const float*)d_in[4];
  const float* bn1m = (const float*)d_in[5];
  const float* bn1v = (const float*)d_in[6];
  const float* w2   = (const float*)d_in[7];
  const float* bn2g = (const float*)d_in[8];
  const float* bn2b = (const float*)d_in[9];
  const float* bn2m = (const float*)d_in[10];
  const float* bn2v = (const float*)d_in[11];
  const float* w3   = (const float*)d_in[12];
  const float* bn3g = (const float*)d_in[13];
  const float* bn3b = (const float*)d_in[14];
  const float* bn3m = (const float*)d_in[15];
  const float* bn3v = (const float*)d_in[16];
  const float* ln1w = (const float*)d_in[17];
  const float* cw   = (const float*)d_in[18];
  const float* cb   = (const float*)d_in[19];
  const float* wi   = (const float*)d_in[20];
  const float* wf   = (const float*)d_in[21];
  const float* wz   = (const float*)d_in[22];
  const float* wo   = (const float*)d_in[23];
  const float* rk   = (const float*)d_in[24];
  const float* rb   = (const float*)d_in[25];
  const float* gnw  = (const float*)d_in[26];
  const float* ln2w = (const float*)d_in[27];
  const float* upw  = (const float*)d_in[28];
  const float* dnw  = (const float*)d_in[29];
  const float* lnpw = (const float*)d_in[30];
  const float* fcw  = (const float*)d_in[31];
  const float* fcb  = (const float*)d_in[32];
  float* outp = (float*)d_out;

  char* ws = (char*)d_ws;
  unsigned short* xnb  = (unsigned short*)ws;                         // [256][510][128] f16 33.4MB
  unsigned short* out2 = (unsigned short*)(ws + ((size_t)64 << 20));  // [256][1022][64] f16 33.5MB
  unsigned int*   gxu  = (unsigned int*)(ws + ((size_t)128 << 20));   // gx f16-pairs 133.7MB
  float* elast = (float*)(ws + ((size_t)258 << 20));
  float* yfin  = (float*)(ws + ((size_t)259 << 20));
  unsigned short* wtg2 = (unsigned short*)(ws + ((size_t)260 << 20));
  unsigned short* wtg3 = (unsigned short*)(ws + ((size_t)260 << 20) + (1 << 20));

  kWTB2<<<dim3(126), 256, 0, stream>>>(w2, w3, wtg2, wtg3);
  kConv12<<<dim3(16, 1, 256), 512, 0, stream>>>(
      x, w1a, w1b, bn1g, bn1b, bn1m, bn1v, wtg2, bn2g, bn2b, bn2m, bn2v, out2);
  kConv3LN<<<dim3(8, 1, 256), 512, 0, stream>>>(
      out2, wtg3, bn3g, bn3b, bn3m, bn3v, ln1w, xnb, elast);
  kGxM<<<dim3(1024), 256, 0, stream>>>(xnb, cw, cb, wi, wf, wz, wo, rb, gxu);
  kRec<<<dim3(1024), 64, 0, stream>>>(gxu, rk, yfin);
  kHead<<<dim3(256), 128, 0, stream>>>(yfin, elast, gnw, ln2w, upw, dnw, lnpw, fcw, fcb, outp);
}